// Round 1
// baseline (2299.010 us; speedup 1.0000x reference)
//
#include <hip/hip_runtime.h>
#include <hip/hip_bf16.h>

// GAE: h1 = relu(gcn(x,W1,b1)); z = gcn(h1,W2,b2); out = sigmoid(dot(Y[src], z[dst]) + bb)
// where Y = z @ Wb[0]  (bilinear refactor: zs^T Wb zd == (zs^T Wb) . zd)

#define N_NODES 50000

// ---------------- degree ----------------
__global__ __launch_bounds__(256) void deg_count(const int* __restrict__ dst,
                                                 float* __restrict__ degf, int E) {
    int e = blockIdx.x * 256 + threadIdx.x;
    if (e < E) atomicAdd(&degf[dst[e]], 1.0f);
}

__global__ __launch_bounds__(256) void deg_fin(const float* __restrict__ degf,
                                               float* __restrict__ dinv,
                                               float* __restrict__ inv, int n) {
    int i = blockIdx.x * 256 + threadIdx.x;
    if (i < n) {
        float d = degf[i] + 1.0f;
        dinv[i] = rsqrtf(d);
        inv[i] = 1.0f / d;
    }
}

// ---------------- GEMM: O[n_rows,COUT] = X[n_rows,K] @ W[K,COUT] ----------------
template <int K, int COUT>
__global__ __launch_bounds__(256) void gemm_kernel(const float* __restrict__ X,
                                                   const float* __restrict__ W,
                                                   float* __restrict__ O, int n_rows) {
    constexpr int NC = COUT / 4;     // float4 column groups
    constexpr int RIF = 256 / NC;    // rows in flight
    constexpr int TR = 16;           // rows per block tile
    constexpr int RPT = TR / RIF;    // rows per thread
    __shared__ float ws[K * COUT];
    __shared__ float xs[TR][K + 4];
    int t = threadIdx.x;
    for (int i = t * 4; i < K * COUT; i += 256 * 4)
        *(float4*)&ws[i] = *(const float4*)&W[i];
    int row0 = blockIdx.x * TR;
    for (int i = t * 4; i < TR * K; i += 256 * 4) {
        int r = i / K, k = i % K;
        int gr = row0 + r;
        float4 v = make_float4(0.f, 0.f, 0.f, 0.f);
        if (gr < n_rows) v = *(const float4*)&X[(size_t)gr * K + k];
        *(float4*)&xs[r][k] = v;
    }
    __syncthreads();
    int cg = t % NC;
    int rsub = t / NC;
    float4 acc[RPT];
#pragma unroll
    for (int rr = 0; rr < RPT; rr++) acc[rr] = make_float4(0.f, 0.f, 0.f, 0.f);
    for (int k = 0; k < K; k++) {
        float4 w4 = *(const float4*)&ws[k * COUT + cg * 4];
#pragma unroll
        for (int rr = 0; rr < RPT; rr++) {
            float xv = xs[rsub + rr * RIF][k];
            acc[rr].x += xv * w4.x;
            acc[rr].y += xv * w4.y;
            acc[rr].z += xv * w4.z;
            acc[rr].w += xv * w4.w;
        }
    }
#pragma unroll
    for (int rr = 0; rr < RPT; rr++) {
        int gr = row0 + rsub + rr * RIF;
        if (gr < n_rows) *(float4*)&O[(size_t)gr * COUT + cg * 4] = acc[rr];
    }
}

// ---------------- edge scatter: agg[dst] += H[src] * dinv[src]*dinv[dst] ----------------
template <int C>
__global__ __launch_bounds__(256) void scatter_kernel(const float* __restrict__ H,
                                                      const int* __restrict__ src,
                                                      const int* __restrict__ dst,
                                                      const float* __restrict__ dinv,
                                                      float* __restrict__ agg, int E) {
    constexpr int TPE = C / 4;
    int tid = blockIdx.x * 256 + threadIdx.x;
    int e = tid / TPE;
    if (e >= E) return;
    int c4 = (tid % TPE) * 4;
    int s = src[e], d = dst[e];
    float norm = dinv[s] * dinv[d];
    float4 h = *(const float4*)&H[(size_t)s * C + c4];
    float* a = &agg[(size_t)d * C + c4];
    atomicAdd(a + 0, h.x * norm);
    atomicAdd(a + 1, h.y * norm);
    atomicAdd(a + 2, h.z * norm);
    atomicAdd(a + 3, h.w * norm);
}

// ---------------- self-loop + bias (+relu): A = act(A + H*inv[n] + b) ----------------
template <int C, bool RELU>
__global__ __launch_bounds__(256) void selfloop_kernel(float* __restrict__ A,
                                                       const float* __restrict__ H,
                                                       const float* __restrict__ inv,
                                                       const float* __restrict__ b, int n) {
    constexpr int TPN = C / 4;
    int tid = blockIdx.x * 256 + threadIdx.x;
    int node = tid / TPN;
    if (node >= n) return;
    int c4 = (tid % TPN) * 4;
    float iv = inv[node];
    float4 a = *(float4*)&A[(size_t)node * C + c4];
    float4 h = *(const float4*)&H[(size_t)node * C + c4];
    float4 bv = *(const float4*)&b[c4];
    a.x += h.x * iv + bv.x;
    a.y += h.y * iv + bv.y;
    a.z += h.z * iv + bv.z;
    a.w += h.w * iv + bv.w;
    if (RELU) {
        a.x = fmaxf(a.x, 0.f);
        a.y = fmaxf(a.y, 0.f);
        a.z = fmaxf(a.z, 0.f);
        a.w = fmaxf(a.w, 0.f);
    }
    *(float4*)&A[(size_t)node * C + c4] = a;
}

// ---------------- decode: out[e] = sigmoid(dot(Y[src], Z[dst]) + bb) ----------------
__global__ __launch_bounds__(256) void decode_kernel(const float* __restrict__ Y,
                                                     const float* __restrict__ Z,
                                                     const int* __restrict__ src,
                                                     const int* __restrict__ dst,
                                                     const float* __restrict__ bb,
                                                     float* __restrict__ out, int E) {
    int tid = blockIdx.x * 256 + threadIdx.x;
    int e = tid / 16;
    int lane = tid % 16;
    if (e >= E) return;
    int s = src[e], d = dst[e];
    float4 y = *(const float4*)&Y[(size_t)s * 64 + lane * 4];
    float4 z = *(const float4*)&Z[(size_t)d * 64 + lane * 4];
    float p = y.x * z.x + y.y * z.y + y.z * z.z + y.w * z.w;
#pragma unroll
    for (int off = 8; off; off >>= 1) p += __shfl_down(p, off, 16);
    if (lane == 0) out[e] = 1.0f / (1.0f + expf(-(p + bb[0])));
}

extern "C" void kernel_launch(void* const* d_in, const int* in_sizes, int n_in,
                              void* d_out, int out_size, void* d_ws, size_t ws_size,
                              hipStream_t stream) {
    const float* x  = (const float*)d_in[0];
    const int*   ei = (const int*)d_in[1];
    const float* W1 = (const float*)d_in[2];
    const float* b1 = (const float*)d_in[3];
    const float* W2 = (const float*)d_in[4];
    const float* b2 = (const float*)d_in[5];
    const float* Wb = (const float*)d_in[6];
    const float* bb = (const float*)d_in[7];
    float* out = (float*)d_out;

    const int N = N_NODES;
    const int E = in_sizes[1] / 2;
    const int* src = ei;
    const int* dst = ei + E;

    float* ws   = (float*)d_ws;
    float* degf = ws;            // [N]
    float* dinv = ws + N;        // [N]
    float* inv  = ws + 2 * N;    // [N]
    float* bufA = ws + 3 * N;    // [N*128]  H1, later H2, later Y
    float* bufB = bufA + (size_t)N * 128;  // [N*128]  A1/h1, later A2/Z

    // degree
    hipMemsetAsync(degf, 0, N * sizeof(float), stream);
    deg_count<<<(E + 255) / 256, 256, 0, stream>>>(dst, degf, E);
    deg_fin<<<(N + 255) / 256, 256, 0, stream>>>(degf, dinv, inv, N);

    // layer 1: H1 = x @ W1
    gemm_kernel<128, 128><<<(N + 15) / 16, 256, 0, stream>>>(x, W1, bufA, N);
    hipMemsetAsync(bufB, 0, (size_t)N * 128 * sizeof(float), stream);
    scatter_kernel<128><<<((size_t)E * 32 + 255) / 256, 256, 0, stream>>>(bufA, src, dst, dinv, bufB, E);
    selfloop_kernel<128, true><<<((size_t)N * 32 + 255) / 256, 256, 0, stream>>>(bufB, bufA, inv, b1, N);

    // layer 2: H2 = h1 @ W2
    gemm_kernel<128, 64><<<(N + 15) / 16, 256, 0, stream>>>(bufB, W2, bufA, N);
    hipMemsetAsync(bufB, 0, (size_t)N * 64 * sizeof(float), stream);
    scatter_kernel<64><<<((size_t)E * 16 + 255) / 256, 256, 0, stream>>>(bufA, src, dst, dinv, bufB, E);
    selfloop_kernel<64, false><<<((size_t)N * 16 + 255) / 256, 256, 0, stream>>>(bufB, bufA, inv, b2, N);

    // decode: Y = Z @ Wb ; out = sigmoid(dot(Y[src], Z[dst]) + bb)
    gemm_kernel<64, 64><<<(N + 15) / 16, 256, 0, stream>>>(bufB, Wb, bufA, N);
    decode_kernel<<<((size_t)E * 16 + 255) / 256, 256, 0, stream>>>(bufA, bufB, src, dst, bb, out, E);
}

// Round 2
// 522.136 us; speedup vs baseline: 4.4031x; 4.4031x over previous
//
#include <hip/hip_runtime.h>
#include <hip/hip_bf16.h>

// GAE: h1 = relu(gcn(x,W1,b1)); z = gcn(h1,W2,b2); out = sigmoid(dot(Y[src], z[dst]) + bb)
// where Y = z @ Wb[0]  (bilinear refactor: zs^T Wb zd == (zs^T Wb) . zd)
// Aggregation is PULL-based over an on-device-built CSR (no f32 atomics).

#define N_NODES 50000

// ---------------- degree histogram (int) ----------------
__global__ __launch_bounds__(256) void deg_count(const int* __restrict__ dst,
                                                 int* __restrict__ degc, int E) {
    int e = blockIdx.x * 256 + threadIdx.x;
    if (e < E) atomicAdd(&degc[dst[e]], 1);
}

__global__ __launch_bounds__(256) void deg_fin(const int* __restrict__ degc,
                                               float* __restrict__ dinv,
                                               float* __restrict__ inv, int n) {
    int i = blockIdx.x * 256 + threadIdx.x;
    if (i < n) {
        float d = (float)degc[i] + 1.0f;
        dinv[i] = rsqrtf(d);
        inv[i] = 1.0f / d;
    }
}

// ---------------- exclusive prefix scan over degc -> row_ptr, cursor ----------------
__global__ __launch_bounds__(1024) void scan_kernel(const int* __restrict__ degc,
                                                    int* __restrict__ row_ptr,
                                                    int* __restrict__ cursor, int n) {
    __shared__ int tmp[1024];
    __shared__ int carry_s;
    if (threadIdx.x == 0) carry_s = 0;
    __syncthreads();
    for (int base = 0; base < n; base += 1024) {
        int i = base + threadIdx.x;
        int v = (i < n) ? degc[i] : 0;
        tmp[threadIdx.x] = v;
        __syncthreads();
        for (int off = 1; off < 1024; off <<= 1) {
            int t = (threadIdx.x >= off) ? tmp[threadIdx.x - off] : 0;
            __syncthreads();
            tmp[threadIdx.x] += t;
            __syncthreads();
        }
        int excl = tmp[threadIdx.x] - v + carry_s;
        if (i < n) { row_ptr[i] = excl; cursor[i] = excl; }
        __syncthreads();
        if (threadIdx.x == 0) carry_s += tmp[1023];
        __syncthreads();
    }
    if (threadIdx.x == 0) row_ptr[n] = carry_s;
}

// ---------------- CSR fill (unsorted within row; sum is order-independent) ----------------
__global__ __launch_bounds__(256) void csr_fill(const int* __restrict__ src,
                                                const int* __restrict__ dst,
                                                int* __restrict__ cursor,
                                                int* __restrict__ col, int E) {
    int e = blockIdx.x * 256 + threadIdx.x;
    if (e < E) {
        int p = atomicAdd(&cursor[dst[e]], 1);
        col[p] = src[e];
    }
}

// ---------------- GEMM: O[n_rows,COUT] = X[n_rows,K] @ W[K,COUT] ----------------
template <int K, int COUT>
__global__ __launch_bounds__(256) void gemm_kernel(const float* __restrict__ X,
                                                   const float* __restrict__ W,
                                                   float* __restrict__ O, int n_rows) {
    constexpr int NC = COUT / 4;     // float4 column groups
    constexpr int RIF = 256 / NC;    // rows in flight
    constexpr int TR = 16;           // rows per block tile
    constexpr int RPT = TR / RIF;    // rows per thread
    __shared__ float ws[K * COUT];
    __shared__ float xs[TR][K + 4];
    int t = threadIdx.x;
    for (int i = t * 4; i < K * COUT; i += 256 * 4)
        *(float4*)&ws[i] = *(const float4*)&W[i];
    int row0 = blockIdx.x * TR;
    for (int i = t * 4; i < TR * K; i += 256 * 4) {
        int r = i / K, k = i % K;
        int gr = row0 + r;
        float4 v = make_float4(0.f, 0.f, 0.f, 0.f);
        if (gr < n_rows) v = *(const float4*)&X[(size_t)gr * K + k];
        *(float4*)&xs[r][k] = v;
    }
    __syncthreads();
    int cg = t % NC;
    int rsub = t / NC;
    float4 acc[RPT];
#pragma unroll
    for (int rr = 0; rr < RPT; rr++) acc[rr] = make_float4(0.f, 0.f, 0.f, 0.f);
    for (int k = 0; k < K; k++) {
        float4 w4 = *(const float4*)&ws[k * COUT + cg * 4];
#pragma unroll
        for (int rr = 0; rr < RPT; rr++) {
            float xv = xs[rsub + rr * RIF][k];
            acc[rr].x += xv * w4.x;
            acc[rr].y += xv * w4.y;
            acc[rr].z += xv * w4.z;
            acc[rr].w += xv * w4.w;
        }
    }
#pragma unroll
    for (int rr = 0; rr < RPT; rr++) {
        int gr = row0 + rsub + rr * RIF;
        if (gr < n_rows) *(float4*)&O[(size_t)gr * COUT + cg * 4] = acc[rr];
    }
}

// ---------------- pull aggregation + self-loop + bias (+relu) ----------------
// O[n] = act( sum_{j in row n} H[col[j]] * dinv[col[j]]*dinv[n]  +  H[n]*inv[n] + b )
template <int C, bool RELU>
__global__ __launch_bounds__(256) void agg_pull(const float* __restrict__ H,
                                                const int* __restrict__ row_ptr,
                                                const int* __restrict__ col,
                                                const float* __restrict__ dinv,
                                                const float* __restrict__ inv,
                                                const float* __restrict__ b,
                                                float* __restrict__ O, int n) {
    constexpr int TPN = C / 4;  // threads per node (each does float4)
    int tid = blockIdx.x * 256 + threadIdx.x;
    int node = tid / TPN;
    if (node >= n) return;
    int c4 = (tid % TPN) * 4;
    float dn = dinv[node];
    float iv = inv[node];
    float4 h = *(const float4*)&H[(size_t)node * C + c4];
    float4 bv = *(const float4*)&b[c4];
    float4 acc = make_float4(h.x * iv + bv.x, h.y * iv + bv.y,
                             h.z * iv + bv.z, h.w * iv + bv.w);
    int j = row_ptr[node];
    int end = row_ptr[node + 1];
    // unroll by 2 for memory-level parallelism
    for (; j + 1 < end; j += 2) {
        int s0 = col[j], s1 = col[j + 1];
        float n0 = dn * dinv[s0], n1 = dn * dinv[s1];
        float4 v0 = *(const float4*)&H[(size_t)s0 * C + c4];
        float4 v1 = *(const float4*)&H[(size_t)s1 * C + c4];
        acc.x += v0.x * n0 + v1.x * n1;
        acc.y += v0.y * n0 + v1.y * n1;
        acc.z += v0.z * n0 + v1.z * n1;
        acc.w += v0.w * n0 + v1.w * n1;
    }
    if (j < end) {
        int s = col[j];
        float nm = dn * dinv[s];
        float4 v = *(const float4*)&H[(size_t)s * C + c4];
        acc.x += v.x * nm;
        acc.y += v.y * nm;
        acc.z += v.z * nm;
        acc.w += v.w * nm;
    }
    if (RELU) {
        acc.x = fmaxf(acc.x, 0.f);
        acc.y = fmaxf(acc.y, 0.f);
        acc.z = fmaxf(acc.z, 0.f);
        acc.w = fmaxf(acc.w, 0.f);
    }
    *(float4*)&O[(size_t)node * C + c4] = acc;
}

// ---------------- decode: out[e] = sigmoid(dot(Y[src], Z[dst]) + bb) ----------------
__global__ __launch_bounds__(256) void decode_kernel(const float* __restrict__ Y,
                                                     const float* __restrict__ Z,
                                                     const int* __restrict__ src,
                                                     const int* __restrict__ dst,
                                                     const float* __restrict__ bb,
                                                     float* __restrict__ out, int E) {
    int tid = blockIdx.x * 256 + threadIdx.x;
    int e = tid / 16;
    int lane = tid % 16;
    if (e >= E) return;
    int s = src[e], d = dst[e];
    float4 y = *(const float4*)&Y[(size_t)s * 64 + lane * 4];
    float4 z = *(const float4*)&Z[(size_t)d * 64 + lane * 4];
    float p = y.x * z.x + y.y * z.y + y.z * z.z + y.w * z.w;
#pragma unroll
    for (int off = 8; off; off >>= 1) p += __shfl_down(p, off, 16);
    if (lane == 0) out[e] = 1.0f / (1.0f + expf(-(p + bb[0])));
}

extern "C" void kernel_launch(void* const* d_in, const int* in_sizes, int n_in,
                              void* d_out, int out_size, void* d_ws, size_t ws_size,
                              hipStream_t stream) {
    const float* x  = (const float*)d_in[0];
    const int*   ei = (const int*)d_in[1];
    const float* W1 = (const float*)d_in[2];
    const float* b1 = (const float*)d_in[3];
    const float* W2 = (const float*)d_in[4];
    const float* b2 = (const float*)d_in[5];
    const float* Wb = (const float*)d_in[6];
    const float* bb = (const float*)d_in[7];
    float* out = (float*)d_out;

    const int N = N_NODES;
    const int E = in_sizes[1] / 2;
    const int* src = ei;
    const int* dst = ei + E;

    // workspace layout
    char* w = (char*)d_ws;
    int*   degc    = (int*)w;                 w += (size_t)N * 4;
    int*   row_ptr = (int*)w;                 w += (size_t)(N + 1) * 4;
    int*   cursor  = (int*)w;                 w += (size_t)N * 4;
    int*   col     = (int*)w;                 w += (size_t)E * 4;
    float* dinv    = (float*)w;               w += (size_t)N * 4;
    float* inv     = (float*)w;               w += (size_t)N * 4;
    float* bufA    = (float*)w;               w += (size_t)N * 128 * 4;  // H1 / H2 / Y
    float* bufB    = (float*)w;               // h1 / Z

    // CSR build + norms
    hipMemsetAsync(degc, 0, (size_t)N * 4, stream);
    deg_count<<<(E + 255) / 256, 256, 0, stream>>>(dst, degc, E);
    deg_fin<<<(N + 255) / 256, 256, 0, stream>>>(degc, dinv, inv, N);
    scan_kernel<<<1, 1024, 0, stream>>>(degc, row_ptr, cursor, N);
    csr_fill<<<(E + 255) / 256, 256, 0, stream>>>(src, dst, cursor, col, E);

    // layer 1: H1 = x @ W1 ; h1 = relu(agg(H1) + selfloop + b1)
    gemm_kernel<128, 128><<<(N + 15) / 16, 256, 0, stream>>>(x, W1, bufA, N);
    agg_pull<128, true><<<((size_t)N * 32 + 255) / 256, 256, 0, stream>>>(
        bufA, row_ptr, col, dinv, inv, b1, bufB, N);

    // layer 2: H2 = h1 @ W2 ; Z = agg(H2) + selfloop + b2
    gemm_kernel<128, 64><<<(N + 15) / 16, 256, 0, stream>>>(bufB, W2, bufA, N);
    agg_pull<64, false><<<((size_t)N * 16 + 255) / 256, 256, 0, stream>>>(
        bufA, row_ptr, col, dinv, inv, b2, bufB + (size_t)N * 64, N);
    float* Z = bufB + (size_t)N * 64;

    // decode: Y = Z @ Wb ; out = sigmoid(dot(Y[src], Z[dst]) + bb)
    gemm_kernel<64, 64><<<(N + 15) / 16, 256, 0, stream>>>(Z, Wb, bufA, N);
    decode_kernel<<<((size_t)E * 16 + 255) / 256, 256, 0, stream>>>(bufA, Z, src, dst, bb, out, E);
}

// Round 3
// 445.970 us; speedup vs baseline: 5.1551x; 1.1708x over previous
//
#include <hip/hip_runtime.h>
#include <hip/hip_bf16.h>

// GAE: h1 = relu(gcn(x,W1,b1)); z = gcn(h1,W2,b2); out = sigmoid(dot(Y[src], z[dst]) + bb)
// where Y = z @ Wb[0]  (bilinear refactor: zs^T Wb zd == (zs^T Wb) . zd)
// Aggregation is PULL-based over an on-device-built CSR (no f32 atomics).
// CSR row_ptr built with a 3-phase parallel grid scan (round-2 single-block scan was 93us @ 0.17% occ).

#define N_NODES 50000

// ---------------- degree histogram (int) ----------------
__global__ __launch_bounds__(256) void deg_count(const int* __restrict__ dst,
                                                 int* __restrict__ degc, int E) {
    int e = blockIdx.x * 256 + threadIdx.x;
    if (e < E) atomicAdd(&degc[dst[e]], 1);
}

__global__ __launch_bounds__(256) void deg_fin(const int* __restrict__ degc,
                                               float* __restrict__ dinv,
                                               float* __restrict__ inv, int n) {
    int i = blockIdx.x * 256 + threadIdx.x;
    if (i < n) {
        float d = (float)degc[i] + 1.0f;
        dinv[i] = rsqrtf(d);
        inv[i] = 1.0f / d;
    }
}

// ---------------- 3-phase exclusive scan: degc -> row_ptr (+cursor copy) ----------------
// phase 1: per-block inclusive scan of 1024 elems; write pre-offset exclusive + block sum
__global__ __launch_bounds__(1024) void scan_phase1(const int* __restrict__ degc,
                                                    int* __restrict__ row_ptr,
                                                    int* __restrict__ blk_sum, int n) {
    __shared__ int tmp[1024];
    int i = blockIdx.x * 1024 + threadIdx.x;
    int v = (i < n) ? degc[i] : 0;
    tmp[threadIdx.x] = v;
    __syncthreads();
    for (int off = 1; off < 1024; off <<= 1) {
        int t = (threadIdx.x >= (unsigned)off) ? tmp[threadIdx.x - off] : 0;
        __syncthreads();
        tmp[threadIdx.x] += t;
        __syncthreads();
    }
    if (i < n) row_ptr[i] = tmp[threadIdx.x] - v;   // exclusive within block
    if (threadIdx.x == 1023) blk_sum[blockIdx.x] = tmp[1023];
}

// phase 2: one wave scans block sums (nblk <= 64); row_ptr[n] = E (known total)
__global__ __launch_bounds__(64) void scan_phase2(int* __restrict__ blk_sum,
                                                  int* __restrict__ row_ptr_n,
                                                  int nblk, int total) {
    int t = threadIdx.x;
    int v = (t < nblk) ? blk_sum[t] : 0;
    int s = v;
#pragma unroll
    for (int off = 1; off < 64; off <<= 1) {
        int u = __shfl_up(s, off, 64);
        if (t >= off) s += u;
    }
    if (t < nblk) blk_sum[t] = s - v;   // exclusive block offset
    if (t == 0) *row_ptr_n = total;
}

// phase 3: add block offset; mirror into cursor
__global__ __launch_bounds__(1024) void scan_phase3(int* __restrict__ row_ptr,
                                                    int* __restrict__ cursor,
                                                    const int* __restrict__ blk_sum, int n) {
    int i = blockIdx.x * 1024 + threadIdx.x;
    if (i < n) {
        int v = row_ptr[i] + blk_sum[blockIdx.x];
        row_ptr[i] = v;
        cursor[i] = v;
    }
}

// ---------------- CSR fill (unsorted within row; sum is order-independent) ----------------
__global__ __launch_bounds__(256) void csr_fill(const int* __restrict__ src,
                                                const int* __restrict__ dst,
                                                int* __restrict__ cursor,
                                                int* __restrict__ col, int E) {
    int e = blockIdx.x * 256 + threadIdx.x;
    if (e < E) {
        int p = atomicAdd(&cursor[dst[e]], 1);
        col[p] = src[e];
    }
}

// ---------------- GEMM: O[n_rows,COUT] = X[n_rows,K] @ W[K,COUT] ----------------
template <int K, int COUT>
__global__ __launch_bounds__(256) void gemm_kernel(const float* __restrict__ X,
                                                   const float* __restrict__ W,
                                                   float* __restrict__ O, int n_rows) {
    constexpr int NC = COUT / 4;     // float4 column groups
    constexpr int RIF = 256 / NC;    // rows in flight
    constexpr int TR = 16;           // rows per block tile
    constexpr int RPT = TR / RIF;    // rows per thread
    __shared__ float ws[K * COUT];
    __shared__ float xs[TR][K + 4];
    int t = threadIdx.x;
    for (int i = t * 4; i < K * COUT; i += 256 * 4)
        *(float4*)&ws[i] = *(const float4*)&W[i];
    int row0 = blockIdx.x * TR;
    for (int i = t * 4; i < TR * K; i += 256 * 4) {
        int r = i / K, k = i % K;
        int gr = row0 + r;
        float4 v = make_float4(0.f, 0.f, 0.f, 0.f);
        if (gr < n_rows) v = *(const float4*)&X[(size_t)gr * K + k];
        *(float4*)&xs[r][k] = v;
    }
    __syncthreads();
    int cg = t % NC;
    int rsub = t / NC;
    float4 acc[RPT];
#pragma unroll
    for (int rr = 0; rr < RPT; rr++) acc[rr] = make_float4(0.f, 0.f, 0.f, 0.f);
    for (int k = 0; k < K; k++) {
        float4 w4 = *(const float4*)&ws[k * COUT + cg * 4];
#pragma unroll
        for (int rr = 0; rr < RPT; rr++) {
            float xv = xs[rsub + rr * RIF][k];
            acc[rr].x += xv * w4.x;
            acc[rr].y += xv * w4.y;
            acc[rr].z += xv * w4.z;
            acc[rr].w += xv * w4.w;
        }
    }
#pragma unroll
    for (int rr = 0; rr < RPT; rr++) {
        int gr = row0 + rsub + rr * RIF;
        if (gr < n_rows) *(float4*)&O[(size_t)gr * COUT + cg * 4] = acc[rr];
    }
}

// ---------------- pull aggregation + self-loop + bias (+relu) ----------------
// O[n] = act( sum_{j in row n} H[col[j]] * dinv[col[j]]*dinv[n]  +  H[n]*inv[n] + b )
template <int C, bool RELU>
__global__ __launch_bounds__(256) void agg_pull(const float* __restrict__ H,
                                                const int* __restrict__ row_ptr,
                                                const int* __restrict__ col,
                                                const float* __restrict__ dinv,
                                                const float* __restrict__ inv,
                                                const float* __restrict__ b,
                                                float* __restrict__ O, int n) {
    constexpr int TPN = C / 4;  // threads per node (each does float4)
    int tid = blockIdx.x * 256 + threadIdx.x;
    int node = tid / TPN;
    if (node >= n) return;
    int c4 = (tid % TPN) * 4;
    float dn = dinv[node];
    float iv = inv[node];
    float4 h = *(const float4*)&H[(size_t)node * C + c4];
    float4 bv = *(const float4*)&b[c4];
    float4 acc = make_float4(h.x * iv + bv.x, h.y * iv + bv.y,
                             h.z * iv + bv.z, h.w * iv + bv.w);
    int j = row_ptr[node];
    int end = row_ptr[node + 1];
    // unroll by 2 for memory-level parallelism
    for (; j + 1 < end; j += 2) {
        int s0 = col[j], s1 = col[j + 1];
        float n0 = dn * dinv[s0], n1 = dn * dinv[s1];
        float4 v0 = *(const float4*)&H[(size_t)s0 * C + c4];
        float4 v1 = *(const float4*)&H[(size_t)s1 * C + c4];
        acc.x += v0.x * n0 + v1.x * n1;
        acc.y += v0.y * n0 + v1.y * n1;
        acc.z += v0.z * n0 + v1.z * n1;
        acc.w += v0.w * n0 + v1.w * n1;
    }
    if (j < end) {
        int s = col[j];
        float nm = dn * dinv[s];
        float4 v = *(const float4*)&H[(size_t)s * C + c4];
        acc.x += v.x * nm;
        acc.y += v.y * nm;
        acc.z += v.z * nm;
        acc.w += v.w * nm;
    }
    if (RELU) {
        acc.x = fmaxf(acc.x, 0.f);
        acc.y = fmaxf(acc.y, 0.f);
        acc.z = fmaxf(acc.z, 0.f);
        acc.w = fmaxf(acc.w, 0.f);
    }
    *(float4*)&O[(size_t)node * C + c4] = acc;
}

// ---------------- decode: out[e] = sigmoid(dot(Y[src], Z[dst]) + bb) ----------------
__global__ __launch_bounds__(256) void decode_kernel(const float* __restrict__ Y,
                                                     const float* __restrict__ Z,
                                                     const int* __restrict__ src,
                                                     const int* __restrict__ dst,
                                                     const float* __restrict__ bb,
                                                     float* __restrict__ out, int E) {
    int tid = blockIdx.x * 256 + threadIdx.x;
    int e = tid / 16;
    int lane = tid % 16;
    if (e >= E) return;
    int s = src[e], d = dst[e];
    float4 y = *(const float4*)&Y[(size_t)s * 64 + lane * 4];
    float4 z = *(const float4*)&Z[(size_t)d * 64 + lane * 4];
    float p = y.x * z.x + y.y * z.y + y.z * z.z + y.w * z.w;
#pragma unroll
    for (int off = 8; off; off >>= 1) p += __shfl_down(p, off, 16);
    if (lane == 0) out[e] = 1.0f / (1.0f + expf(-(p + bb[0])));
}

extern "C" void kernel_launch(void* const* d_in, const int* in_sizes, int n_in,
                              void* d_out, int out_size, void* d_ws, size_t ws_size,
                              hipStream_t stream) {
    const float* x  = (const float*)d_in[0];
    const int*   ei = (const int*)d_in[1];
    const float* W1 = (const float*)d_in[2];
    const float* b1 = (const float*)d_in[3];
    const float* W2 = (const float*)d_in[4];
    const float* b2 = (const float*)d_in[5];
    const float* Wb = (const float*)d_in[6];
    const float* bb = (const float*)d_in[7];
    float* out = (float*)d_out;

    const int N = N_NODES;
    const int E = in_sizes[1] / 2;
    const int* src = ei;
    const int* dst = ei + E;

    const int NBLK = (N + 1023) / 1024;  // 49 for N=50000

    // workspace layout
    char* w = (char*)d_ws;
    int*   degc    = (int*)w;                 w += (size_t)N * 4;
    int*   row_ptr = (int*)w;                 w += (size_t)(N + 1) * 4;
    int*   cursor  = (int*)w;                 w += (size_t)N * 4;
    int*   blk_sum = (int*)w;                 w += (size_t)64 * 4;
    int*   col     = (int*)w;                 w += (size_t)E * 4;
    float* dinv    = (float*)w;               w += (size_t)N * 4;
    float* inv     = (float*)w;               w += (size_t)N * 4;
    float* bufA    = (float*)w;               w += (size_t)N * 128 * 4;  // H1 / H2 / Y
    float* bufB    = (float*)w;               // h1 / Z

    // CSR build + norms
    hipMemsetAsync(degc, 0, (size_t)N * 4, stream);
    deg_count<<<(E + 255) / 256, 256, 0, stream>>>(dst, degc, E);
    deg_fin<<<(N + 255) / 256, 256, 0, stream>>>(degc, dinv, inv, N);
    scan_phase1<<<NBLK, 1024, 0, stream>>>(degc, row_ptr, blk_sum, N);
    scan_phase2<<<1, 64, 0, stream>>>(blk_sum, row_ptr + N, NBLK, E);
    scan_phase3<<<NBLK, 1024, 0, stream>>>(row_ptr, cursor, blk_sum, N);
    csr_fill<<<(E + 255) / 256, 256, 0, stream>>>(src, dst, cursor, col, E);

    // layer 1: H1 = x @ W1 ; h1 = relu(agg(H1) + selfloop + b1)
    gemm_kernel<128, 128><<<(N + 15) / 16, 256, 0, stream>>>(x, W1, bufA, N);
    agg_pull<128, true><<<((size_t)N * 32 + 255) / 256, 256, 0, stream>>>(
        bufA, row_ptr, col, dinv, inv, b1, bufB, N);

    // layer 2: H2 = h1 @ W2 ; Z = agg(H2) + selfloop + b2
    gemm_kernel<128, 64><<<(N + 15) / 16, 256, 0, stream>>>(bufB, W2, bufA, N);
    agg_pull<64, false><<<((size_t)N * 16 + 255) / 256, 256, 0, stream>>>(
        bufA, row_ptr, col, dinv, inv, b2, bufB + (size_t)N * 64, N);
    float* Z = bufB + (size_t)N * 64;

    // decode: Y = Z @ Wb ; out = sigmoid(dot(Y[src], Z[dst]) + bb)
    gemm_kernel<64, 64><<<(N + 15) / 16, 256, 0, stream>>>(Z, Wb, bufA, N);
    decode_kernel<<<((size_t)E * 16 + 255) / 256, 256, 0, stream>>>(bufA, Z, src, dst, bb, out, E);
}

// Round 4
// 367.186 us; speedup vs baseline: 6.2612x; 1.2146x over previous
//
#include <hip/hip_runtime.h>
#include <hip/hip_bf16.h>

// GAE: h1 = relu(gcn(x,W1,b1)); z = gcn(h1,W2,b2); out = sigmoid(dot(Y[src], z[dst]) + bb)
// where Y = z @ Wb[0]  (bilinear refactor).
// PULL aggregation over on-device CSR. All randomly-gathered node matrices
// (H1, h1, H2, Z, Y) stored bf16 to halve gather bytes (agg/decode are
// gather-BW-bound: 228 MB FETCH at f32). GEMMs accumulate f32.

#define N_NODES 50000
typedef unsigned int u32;
typedef unsigned short u16;

__device__ __forceinline__ float bflo(u32 u) { return __uint_as_float(u << 16); }
__device__ __forceinline__ float bfhi(u32 u) { return __uint_as_float(u & 0xffff0000u); }
__device__ __forceinline__ u32 f2bf(float f) {  // round-to-nearest-even, returns low 16
    u32 b = __float_as_uint(f);
    return (b + 0x7fffu + ((b >> 16) & 1u)) >> 16;
}
__device__ __forceinline__ u32 pack2(float a, float b) { return f2bf(a) | (f2bf(b) << 16); }

// ---------------- degree histogram (int) ----------------
__global__ __launch_bounds__(256) void deg_count(const int* __restrict__ dst,
                                                 int* __restrict__ degc, int E) {
    int e = blockIdx.x * 256 + threadIdx.x;
    if (e < E) atomicAdd(&degc[dst[e]], 1);
}

__global__ __launch_bounds__(256) void deg_fin(const int* __restrict__ degc,
                                               float* __restrict__ dinv,
                                               float* __restrict__ inv, int n) {
    int i = blockIdx.x * 256 + threadIdx.x;
    if (i < n) {
        float d = (float)degc[i] + 1.0f;
        dinv[i] = rsqrtf(d);
        inv[i] = 1.0f / d;
    }
}

// ---------------- 3-phase exclusive scan: degc -> row_ptr (+cursor copy) ----------------
__global__ __launch_bounds__(1024) void scan_phase1(const int* __restrict__ degc,
                                                    int* __restrict__ row_ptr,
                                                    int* __restrict__ blk_sum, int n) {
    __shared__ int tmp[1024];
    int i = blockIdx.x * 1024 + threadIdx.x;
    int v = (i < n) ? degc[i] : 0;
    tmp[threadIdx.x] = v;
    __syncthreads();
    for (int off = 1; off < 1024; off <<= 1) {
        int t = (threadIdx.x >= (unsigned)off) ? tmp[threadIdx.x - off] : 0;
        __syncthreads();
        tmp[threadIdx.x] += t;
        __syncthreads();
    }
    if (i < n) row_ptr[i] = tmp[threadIdx.x] - v;
    if (threadIdx.x == 1023) blk_sum[blockIdx.x] = tmp[1023];
}

__global__ __launch_bounds__(64) void scan_phase2(int* __restrict__ blk_sum,
                                                  int* __restrict__ row_ptr_n,
                                                  int nblk, int total) {
    int t = threadIdx.x;
    int v = (t < nblk) ? blk_sum[t] : 0;
    int s = v;
#pragma unroll
    for (int off = 1; off < 64; off <<= 1) {
        int u = __shfl_up(s, off, 64);
        if (t >= off) s += u;
    }
    if (t < nblk) blk_sum[t] = s - v;
    if (t == 0) *row_ptr_n = total;
}

__global__ __launch_bounds__(1024) void scan_phase3(int* __restrict__ row_ptr,
                                                    int* __restrict__ cursor,
                                                    const int* __restrict__ blk_sum, int n) {
    int i = blockIdx.x * 1024 + threadIdx.x;
    if (i < n) {
        int v = row_ptr[i] + blk_sum[blockIdx.x];
        row_ptr[i] = v;
        cursor[i] = v;
    }
}

// ---------------- CSR fill ----------------
__global__ __launch_bounds__(256) void csr_fill(const int* __restrict__ src,
                                                const int* __restrict__ dst,
                                                int* __restrict__ cursor,
                                                int* __restrict__ col, int E) {
    int e = blockIdx.x * 256 + threadIdx.x;
    if (e < E) {
        int p = atomicAdd(&cursor[dst[e]], 1);
        col[p] = src[e];
    }
}

// ---------------- GEMM: O[n_rows,COUT](bf16) = X[n_rows,K] @ W[K,COUT] ----------------
// BF16_IN: X is bf16 (u16*), else f32. W is f32. Accumulate f32, store bf16.
template <int K, int COUT, bool BF16_IN>
__global__ __launch_bounds__(256) void gemm_kernel(const void* __restrict__ Xv,
                                                   const float* __restrict__ W,
                                                   u16* __restrict__ O, int n_rows) {
    constexpr int NC = COUT / 4;
    constexpr int RIF = 256 / NC;
    constexpr int TR = 16;
    constexpr int RPT = TR / RIF;
    __shared__ float ws[K * COUT];
    __shared__ float xs[TR][K + 4];
    int t = threadIdx.x;
    for (int i = t * 4; i < K * COUT; i += 256 * 4)
        *(float4*)&ws[i] = *(const float4*)&W[i];
    int row0 = blockIdx.x * TR;
    if (BF16_IN) {
        const uint4* X = (const uint4*)Xv;  // 8 bf16 per uint4
        for (int i = t * 8; i < TR * K; i += 256 * 8) {
            int r = i / K, k = i % K;
            int gr = row0 + r;
            uint4 v = make_uint4(0, 0, 0, 0);
            if (gr < n_rows) v = X[((size_t)gr * K + k) / 8];
            xs[r][k + 0] = bflo(v.x); xs[r][k + 1] = bfhi(v.x);
            xs[r][k + 2] = bflo(v.y); xs[r][k + 3] = bfhi(v.y);
            xs[r][k + 4] = bflo(v.z); xs[r][k + 5] = bfhi(v.z);
            xs[r][k + 6] = bflo(v.w); xs[r][k + 7] = bfhi(v.w);
        }
    } else {
        const float* X = (const float*)Xv;
        for (int i = t * 4; i < TR * K; i += 256 * 4) {
            int r = i / K, k = i % K;
            int gr = row0 + r;
            float4 v = make_float4(0.f, 0.f, 0.f, 0.f);
            if (gr < n_rows) v = *(const float4*)&X[(size_t)gr * K + k];
            *(float4*)&xs[r][k] = v;
        }
    }
    __syncthreads();
    int cg = t % NC;
    int rsub = t / NC;
    float4 acc[RPT];
#pragma unroll
    for (int rr = 0; rr < RPT; rr++) acc[rr] = make_float4(0.f, 0.f, 0.f, 0.f);
    for (int k = 0; k < K; k++) {
        float4 w4 = *(const float4*)&ws[k * COUT + cg * 4];
#pragma unroll
        for (int rr = 0; rr < RPT; rr++) {
            float xv = xs[rsub + rr * RIF][k];
            acc[rr].x += xv * w4.x;
            acc[rr].y += xv * w4.y;
            acc[rr].z += xv * w4.z;
            acc[rr].w += xv * w4.w;
        }
    }
#pragma unroll
    for (int rr = 0; rr < RPT; rr++) {
        int gr = row0 + rsub + rr * RIF;
        if (gr < n_rows) {
            uint2 p;
            p.x = pack2(acc[rr].x, acc[rr].y);
            p.y = pack2(acc[rr].z, acc[rr].w);
            *(uint2*)&O[(size_t)gr * COUT + cg * 4] = p;
        }
    }
}

// ---------------- pull aggregation + self-loop + bias (+relu), bf16 in/out ----------------
// O[n] = act( sum_{j in row n} H[col[j]] * dinv[col[j]]*dinv[n] + H[n]*inv[n] + b )
template <int C, bool RELU>
__global__ __launch_bounds__(256) void agg_pull(const u16* __restrict__ H,
                                                const int* __restrict__ row_ptr,
                                                const int* __restrict__ col,
                                                const float* __restrict__ dinv,
                                                const float* __restrict__ inv,
                                                const float* __restrict__ b,
                                                u16* __restrict__ O, int n) {
    constexpr int TPN = C / 8;  // threads per node, 8 bf16 (16 B) each
    const uint4* Hv = (const uint4*)H;
    int tid = blockIdx.x * 256 + threadIdx.x;
    int node = tid / TPN;
    if (node >= n) return;
    int part = tid % TPN;
    int c8 = part * 8;
    float dn = dinv[node];
    float iv = inv[node];
    float acc[8];
    {
        uint4 h = Hv[(size_t)node * TPN + part];
        acc[0] = bflo(h.x) * iv + b[c8 + 0];
        acc[1] = bfhi(h.x) * iv + b[c8 + 1];
        acc[2] = bflo(h.y) * iv + b[c8 + 2];
        acc[3] = bfhi(h.y) * iv + b[c8 + 3];
        acc[4] = bflo(h.z) * iv + b[c8 + 4];
        acc[5] = bfhi(h.z) * iv + b[c8 + 5];
        acc[6] = bflo(h.w) * iv + b[c8 + 6];
        acc[7] = bfhi(h.w) * iv + b[c8 + 7];
    }
    int j = row_ptr[node];
    int end = row_ptr[node + 1];
    for (; j + 3 < end; j += 4) {
        int s0 = col[j], s1 = col[j + 1], s2 = col[j + 2], s3 = col[j + 3];
        float n0 = dn * dinv[s0], n1 = dn * dinv[s1];
        float n2 = dn * dinv[s2], n3 = dn * dinv[s3];
        uint4 v0 = Hv[(size_t)s0 * TPN + part];
        uint4 v1 = Hv[(size_t)s1 * TPN + part];
        uint4 v2 = Hv[(size_t)s2 * TPN + part];
        uint4 v3 = Hv[(size_t)s3 * TPN + part];
        acc[0] += bflo(v0.x) * n0 + bflo(v1.x) * n1 + bflo(v2.x) * n2 + bflo(v3.x) * n3;
        acc[1] += bfhi(v0.x) * n0 + bfhi(v1.x) * n1 + bfhi(v2.x) * n2 + bfhi(v3.x) * n3;
        acc[2] += bflo(v0.y) * n0 + bflo(v1.y) * n1 + bflo(v2.y) * n2 + bflo(v3.y) * n3;
        acc[3] += bfhi(v0.y) * n0 + bfhi(v1.y) * n1 + bfhi(v2.y) * n2 + bfhi(v3.y) * n3;
        acc[4] += bflo(v0.z) * n0 + bflo(v1.z) * n1 + bflo(v2.z) * n2 + bflo(v3.z) * n3;
        acc[5] += bfhi(v0.z) * n0 + bfhi(v1.z) * n1 + bfhi(v2.z) * n2 + bfhi(v3.z) * n3;
        acc[6] += bflo(v0.w) * n0 + bflo(v1.w) * n1 + bflo(v2.w) * n2 + bflo(v3.w) * n3;
        acc[7] += bfhi(v0.w) * n0 + bfhi(v1.w) * n1 + bfhi(v2.w) * n2 + bfhi(v3.w) * n3;
    }
    for (; j < end; j++) {
        int s = col[j];
        float nm = dn * dinv[s];
        uint4 v = Hv[(size_t)s * TPN + part];
        acc[0] += bflo(v.x) * nm; acc[1] += bfhi(v.x) * nm;
        acc[2] += bflo(v.y) * nm; acc[3] += bfhi(v.y) * nm;
        acc[4] += bflo(v.z) * nm; acc[5] += bfhi(v.z) * nm;
        acc[6] += bflo(v.w) * nm; acc[7] += bfhi(v.w) * nm;
    }
    if (RELU) {
#pragma unroll
        for (int i = 0; i < 8; i++) acc[i] = fmaxf(acc[i], 0.f);
    }
    uint4 o;
    o.x = pack2(acc[0], acc[1]);
    o.y = pack2(acc[2], acc[3]);
    o.z = pack2(acc[4], acc[5]);
    o.w = pack2(acc[6], acc[7]);
    ((uint4*)O)[(size_t)node * TPN + part] = o;
}

// ---------------- decode: out[e] = sigmoid(dot(Y[src], Z[dst]) + bb), bf16 in ----------------
__global__ __launch_bounds__(256) void decode_kernel(const u16* __restrict__ Y,
                                                     const u16* __restrict__ Z,
                                                     const int* __restrict__ src,
                                                     const int* __restrict__ dst,
                                                     const float* __restrict__ bb,
                                                     float* __restrict__ out, int E) {
    const uint4* Yv = (const uint4*)Y;  // 8 uint4 per 64-wide row
    const uint4* Zv = (const uint4*)Z;
    int tid = blockIdx.x * 256 + threadIdx.x;
    int e = tid / 8;
    int lane = tid % 8;
    if (e >= E) return;
    int s = src[e], d = dst[e];
    uint4 y = Yv[(size_t)s * 8 + lane];
    uint4 z = Zv[(size_t)d * 8 + lane];
    float p = bflo(y.x) * bflo(z.x) + bfhi(y.x) * bfhi(z.x)
            + bflo(y.y) * bflo(z.y) + bfhi(y.y) * bfhi(z.y)
            + bflo(y.z) * bflo(z.z) + bfhi(y.z) * bfhi(z.z)
            + bflo(y.w) * bflo(z.w) + bfhi(y.w) * bfhi(z.w);
    p += __shfl_down(p, 4, 8);
    p += __shfl_down(p, 2, 8);
    p += __shfl_down(p, 1, 8);
    if (lane == 0) out[e] = 1.0f / (1.0f + expf(-(p + bb[0])));
}

extern "C" void kernel_launch(void* const* d_in, const int* in_sizes, int n_in,
                              void* d_out, int out_size, void* d_ws, size_t ws_size,
                              hipStream_t stream) {
    const float* x  = (const float*)d_in[0];
    const int*   ei = (const int*)d_in[1];
    const float* W1 = (const float*)d_in[2];
    const float* b1 = (const float*)d_in[3];
    const float* W2 = (const float*)d_in[4];
    const float* b2 = (const float*)d_in[5];
    const float* Wb = (const float*)d_in[6];
    const float* bb = (const float*)d_in[7];
    float* out = (float*)d_out;

    const int N = N_NODES;
    const int E = in_sizes[1] / 2;
    const int* src = ei;
    const int* dst = ei + E;
    const int NBLK = (N + 1023) / 1024;

    // workspace layout
    char* w = (char*)d_ws;
    int*   degc    = (int*)w;   w += (size_t)N * 4;
    int*   row_ptr = (int*)w;   w += (size_t)(N + 1) * 4;
    int*   cursor  = (int*)w;   w += (size_t)N * 4;
    int*   blk_sum = (int*)w;   w += (size_t)64 * 4;
    int*   col     = (int*)w;   w += (size_t)E * 4;
    float* dinv    = (float*)w; w += (size_t)N * 4;
    float* inv     = (float*)w; w += (size_t)N * 4;
    w = (char*)(((size_t)w + 15) & ~(size_t)15);
    u16* bufA = (u16*)w;        w += (size_t)N * 128 * 2;  // H1; later H2 (first half) + Y (second half)
    u16* bufB = (u16*)w;        w += (size_t)N * 128 * 2;  // h1
    u16* bufC = (u16*)w;                                   // Z

    u16* H1 = bufA;
    u16* h1 = bufB;
    u16* H2 = bufA;                       // H1 dead after agg1
    u16* Z  = bufC;
    u16* Y  = bufA + (size_t)N * 64;      // second half of bufA (H2 in first half, still live? no - dead after agg2; safe either way)

    // CSR build + norms
    hipMemsetAsync(degc, 0, (size_t)N * 4, stream);
    deg_count<<<(E + 255) / 256, 256, 0, stream>>>(dst, degc, E);
    deg_fin<<<(N + 255) / 256, 256, 0, stream>>>(degc, dinv, inv, N);
    scan_phase1<<<NBLK, 1024, 0, stream>>>(degc, row_ptr, blk_sum, N);
    scan_phase2<<<1, 64, 0, stream>>>(blk_sum, row_ptr + N, NBLK, E);
    scan_phase3<<<NBLK, 1024, 0, stream>>>(row_ptr, cursor, blk_sum, N);
    csr_fill<<<(E + 255) / 256, 256, 0, stream>>>(src, dst, cursor, col, E);

    // layer 1
    gemm_kernel<128, 128, false><<<(N + 15) / 16, 256, 0, stream>>>(x, W1, H1, N);
    agg_pull<128, true><<<((size_t)N * 16 + 255) / 256, 256, 0, stream>>>(
        H1, row_ptr, col, dinv, inv, b1, h1, N);

    // layer 2
    gemm_kernel<128, 64, true><<<(N + 15) / 16, 256, 0, stream>>>(h1, W2, H2, N);
    agg_pull<64, false><<<((size_t)N * 8 + 255) / 256, 256, 0, stream>>>(
        H2, row_ptr, col, dinv, inv, b2, Z, N);

    // decode
    gemm_kernel<64, 64, true><<<(N + 15) / 16, 256, 0, stream>>>(Z, Wb, Y, N);
    decode_kernel<<<((size_t)E * 8 + 255) / 256, 256, 0, stream>>>(Y, Z, src, dst, bb, out, E);
}

// Round 5
// 320.131 us; speedup vs baseline: 7.1815x; 1.1470x over previous
//
#include <hip/hip_runtime.h>
#include <hip/hip_bf16.h>

// GAE: h1 = relu(gcn(x,W1,b1)); z = gcn(h1,W2,b2); out = sigmoid(dot(Y[src], z[dst]) + bb)
// where Y = z @ Wb[0]  (bilinear refactor).
// PULL aggregation over on-device CSR; gathered node matrices bf16.
// GEMMs: MFMA bf16 with split-bf16 (hi+lo) emulation of f32 for the f32-side
// operands (x, W1, W2, Wb) so numerics match the round-4 passing version.

#define N_NODES 50000
typedef unsigned int u32;
typedef unsigned short u16;

typedef __attribute__((ext_vector_type(8))) short bf16x8;
typedef __attribute__((ext_vector_type(4))) float f32x4;
union frag_u { bf16x8 f; u32 u[4]; uint4 v; };

__device__ __forceinline__ float bflo(u32 u) { return __uint_as_float(u << 16); }
__device__ __forceinline__ float bfhi(u32 u) { return __uint_as_float(u & 0xffff0000u); }
__device__ __forceinline__ u32 f2bf(float f) {  // RNE, returns low 16
    u32 b = __float_as_uint(f);
    return (b + 0x7fffu + ((b >> 16) & 1u)) >> 16;
}
__device__ __forceinline__ u32 pack2(float a, float b) { return f2bf(a) | (f2bf(b) << 16); }

// ---------------- degree histogram (int) ----------------
__global__ __launch_bounds__(256) void deg_count(const int* __restrict__ dst,
                                                 int* __restrict__ degc, int E) {
    int e = blockIdx.x * 256 + threadIdx.x;
    if (e < E) atomicAdd(&degc[dst[e]], 1);
}

__global__ __launch_bounds__(256) void deg_fin(const int* __restrict__ degc,
                                               float* __restrict__ dinv,
                                               float* __restrict__ inv, int n) {
    int i = blockIdx.x * 256 + threadIdx.x;
    if (i < n) {
        float d = (float)degc[i] + 1.0f;
        dinv[i] = rsqrtf(d);
        inv[i] = 1.0f / d;
    }
}

// ---------------- 3-phase exclusive scan: degc -> row_ptr (+cursor copy) ----------------
__global__ __launch_bounds__(1024) void scan_phase1(const int* __restrict__ degc,
                                                    int* __restrict__ row_ptr,
                                                    int* __restrict__ blk_sum, int n) {
    __shared__ int tmp[1024];
    int i = blockIdx.x * 1024 + threadIdx.x;
    int v = (i < n) ? degc[i] : 0;
    tmp[threadIdx.x] = v;
    __syncthreads();
    for (int off = 1; off < 1024; off <<= 1) {
        int t = (threadIdx.x >= (unsigned)off) ? tmp[threadIdx.x - off] : 0;
        __syncthreads();
        tmp[threadIdx.x] += t;
        __syncthreads();
    }
    if (i < n) row_ptr[i] = tmp[threadIdx.x] - v;
    if (threadIdx.x == 1023) blk_sum[blockIdx.x] = tmp[1023];
}

__global__ __launch_bounds__(64) void scan_phase2(int* __restrict__ blk_sum,
                                                  int* __restrict__ row_ptr_n,
                                                  int nblk, int total) {
    int t = threadIdx.x;
    int v = (t < nblk) ? blk_sum[t] : 0;
    int s = v;
#pragma unroll
    for (int off = 1; off < 64; off <<= 1) {
        int u = __shfl_up(s, off, 64);
        if (t >= off) s += u;
    }
    if (t < nblk) blk_sum[t] = s - v;
    if (t == 0) *row_ptr_n = total;
}

__global__ __launch_bounds__(1024) void scan_phase3(int* __restrict__ row_ptr,
                                                    int* __restrict__ cursor,
                                                    const int* __restrict__ blk_sum, int n) {
    int i = blockIdx.x * 1024 + threadIdx.x;
    if (i < n) {
        int v = row_ptr[i] + blk_sum[blockIdx.x];
        row_ptr[i] = v;
        cursor[i] = v;
    }
}

// ---------------- CSR fill ----------------
__global__ __launch_bounds__(256) void csr_fill(const int* __restrict__ src,
                                                const int* __restrict__ dst,
                                                int* __restrict__ cursor,
                                                int* __restrict__ col, int E) {
    int e = blockIdx.x * 256 + threadIdx.x;
    if (e < E) {
        int p = atomicAdd(&cursor[dst[e]], 1);
        col[p] = src[e];
    }
}

// ---------------- MFMA GEMM: O[n_rows,NOUT](bf16) = X[n_rows,K] @ W[K,NOUT](f32) ----------------
// A_BF16: X is bf16 (exact, single frag); else f32 (split hi/lo, 2-term).
// W always f32 -> split hi/lo in LDS (transposed, padded).
// Layouts (HW-verified, learn_hip m89/m91/m120):
//   A[m=lane&15][k=quad*8+j], B[k=quad*8+j][n=lane&15], D: col=lane&15, row=quad*4+reg.
template <int K, int NOUT, bool A_BF16>
__global__ __launch_bounds__(256) void gemm_mfma(const void* __restrict__ Xv,
                                                 const float* __restrict__ W,
                                                 u16* __restrict__ O, int n_rows) {
    constexpr int KP = K + 8;       // padded LDS row (bf16 elems): bank stride 68 words -> 2-way (free)
    constexpr int NT = NOUT / 16;   // n-tiles
    constexpr int KS = K / 32;      // k-steps
    __shared__ __align__(16) u16 Wt_hi[NOUT * KP];
    __shared__ __align__(16) u16 Wt_lo[NOUT * KP];
    int t = threadIdx.x;
    // stage W (f32 [K][NOUT]) -> transposed split-bf16 LDS
    for (int i4 = t; i4 < K * NOUT / 4; i4 += 256) {
        int k = (i4 * 4) / NOUT;
        int n0 = (i4 * 4) % NOUT;
        float4 w4 = *(const float4*)&W[(size_t)k * NOUT + n0];
        float wv[4] = {w4.x, w4.y, w4.z, w4.w};
#pragma unroll
        for (int q = 0; q < 4; q++) {
            u32 hi = f2bf(wv[q]);
            u32 lo = f2bf(wv[q] - bflo(hi));
            Wt_hi[(n0 + q) * KP + k] = (u16)hi;
            Wt_lo[(n0 + q) * KP + k] = (u16)lo;
        }
    }
    __syncthreads();

    int wave = t >> 6;
    int lane = t & 63;
    int m16 = lane & 15;
    int quad = lane >> 4;
    int row0 = blockIdx.x * 128 + wave * 32;  // 2 m-tiles of 16 rows per wave

    f32x4 acc[2][NT] = {};
    for (int ks = 0; ks < KS; ks++) {
        frag_u a_hi[2], a_lo[2];
#pragma unroll
        for (int mt = 0; mt < 2; mt++) {
            int row = row0 + mt * 16 + m16;
            row = row < n_rows ? row : n_rows - 1;  // clamp (tail reads safe, stores bounded)
            if (A_BF16) {
                a_hi[mt].v = *(const uint4*)((const u16*)Xv + (size_t)row * K + ks * 32 + quad * 8);
            } else {
                const float* X = (const float*)Xv + (size_t)row * K + ks * 32 + quad * 8;
                float4 x0 = *(const float4*)X;
                float4 x1 = *(const float4*)(X + 4);
                float xv[8] = {x0.x, x0.y, x0.z, x0.w, x1.x, x1.y, x1.z, x1.w};
#pragma unroll
                for (int p = 0; p < 4; p++) {
                    u32 h0 = f2bf(xv[2 * p]), h1 = f2bf(xv[2 * p + 1]);
                    a_hi[mt].u[p] = h0 | (h1 << 16);
                    a_lo[mt].u[p] = pack2(xv[2 * p] - bflo(h0), xv[2 * p + 1] - bflo(h1));
                }
            }
        }
#pragma unroll
        for (int nt = 0; nt < NT; nt++) {
            int n = nt * 16 + m16;
            frag_u b_hi, b_lo;
            b_hi.v = *(const uint4*)&Wt_hi[n * KP + ks * 32 + quad * 8];
            b_lo.v = *(const uint4*)&Wt_lo[n * KP + ks * 32 + quad * 8];
#pragma unroll
            for (int mt = 0; mt < 2; mt++) {
                acc[mt][nt] = __builtin_amdgcn_mfma_f32_16x16x32_bf16(a_hi[mt].f, b_hi.f, acc[mt][nt], 0, 0, 0);
                acc[mt][nt] = __builtin_amdgcn_mfma_f32_16x16x32_bf16(a_hi[mt].f, b_lo.f, acc[mt][nt], 0, 0, 0);
                if (!A_BF16)
                    acc[mt][nt] = __builtin_amdgcn_mfma_f32_16x16x32_bf16(a_lo[mt].f, b_hi.f, acc[mt][nt], 0, 0, 0);
            }
        }
    }
    // epilogue: D col=lane&15, row=quad*4+reg
#pragma unroll
    for (int mt = 0; mt < 2; mt++)
#pragma unroll
        for (int nt = 0; nt < NT; nt++)
#pragma unroll
            for (int r = 0; r < 4; r++) {
                int row = row0 + mt * 16 + quad * 4 + r;
                if (row < n_rows)
                    O[(size_t)row * NOUT + nt * 16 + m16] = (u16)f2bf(acc[mt][nt][r]);
            }
}

// ---------------- pull aggregation + self-loop + bias (+relu), bf16 in/out ----------------
template <int C, bool RELU>
__global__ __launch_bounds__(256) void agg_pull(const u16* __restrict__ H,
                                                const int* __restrict__ row_ptr,
                                                const int* __restrict__ col,
                                                const float* __restrict__ dinv,
                                                const float* __restrict__ inv,
                                                const float* __restrict__ b,
                                                u16* __restrict__ O, int n) {
    constexpr int TPN = C / 8;
    const uint4* Hv = (const uint4*)H;
    int tid = blockIdx.x * 256 + threadIdx.x;
    int node = tid / TPN;
    if (node >= n) return;
    int part = tid % TPN;
    int c8 = part * 8;
    float dn = dinv[node];
    float iv = inv[node];
    float acc[8];
    {
        uint4 h = Hv[(size_t)node * TPN + part];
        acc[0] = bflo(h.x) * iv + b[c8 + 0];
        acc[1] = bfhi(h.x) * iv + b[c8 + 1];
        acc[2] = bflo(h.y) * iv + b[c8 + 2];
        acc[3] = bfhi(h.y) * iv + b[c8 + 3];
        acc[4] = bflo(h.z) * iv + b[c8 + 4];
        acc[5] = bfhi(h.z) * iv + b[c8 + 5];
        acc[6] = bflo(h.w) * iv + b[c8 + 6];
        acc[7] = bfhi(h.w) * iv + b[c8 + 7];
    }
    int j = row_ptr[node];
    int end = row_ptr[node + 1];
    for (; j + 3 < end; j += 4) {
        int s0 = col[j], s1 = col[j + 1], s2 = col[j + 2], s3 = col[j + 3];
        float n0 = dn * dinv[s0], n1 = dn * dinv[s1];
        float n2 = dn * dinv[s2], n3 = dn * dinv[s3];
        uint4 v0 = Hv[(size_t)s0 * TPN + part];
        uint4 v1 = Hv[(size_t)s1 * TPN + part];
        uint4 v2 = Hv[(size_t)s2 * TPN + part];
        uint4 v3 = Hv[(size_t)s3 * TPN + part];
        acc[0] += bflo(v0.x) * n0 + bflo(v1.x) * n1 + bflo(v2.x) * n2 + bflo(v3.x) * n3;
        acc[1] += bfhi(v0.x) * n0 + bfhi(v1.x) * n1 + bfhi(v2.x) * n2 + bfhi(v3.x) * n3;
        acc[2] += bflo(v0.y) * n0 + bflo(v1.y) * n1 + bflo(v2.y) * n2 + bflo(v3.y) * n3;
        acc[3] += bfhi(v0.y) * n0 + bfhi(v1.y) * n1 + bfhi(v2.y) * n2 + bfhi(v3.y) * n3;
        acc[4] += bflo(v0.z) * n0 + bflo(v1.z) * n1 + bflo(v2.z) * n2 + bflo(v3.z) * n3;
        acc[5] += bfhi(v0.z) * n0 + bfhi(v1.z) * n1 + bfhi(v2.z) * n2 + bfhi(v3.z) * n3;
        acc[6] += bflo(v0.w) * n0 + bflo(v1.w) * n1 + bflo(v2.w) * n2 + bflo(v3.w) * n3;
        acc[7] += bfhi(v0.w) * n0 + bfhi(v1.w) * n1 + bfhi(v2.w) * n2 + bfhi(v3.w) * n3;
    }
    for (; j < end; j++) {
        int s = col[j];
        float nm = dn * dinv[s];
        uint4 v = Hv[(size_t)s * TPN + part];
        acc[0] += bflo(v.x) * nm; acc[1] += bfhi(v.x) * nm;
        acc[2] += bflo(v.y) * nm; acc[3] += bfhi(v.y) * nm;
        acc[4] += bflo(v.z) * nm; acc[5] += bfhi(v.z) * nm;
        acc[6] += bflo(v.w) * nm; acc[7] += bfhi(v.w) * nm;
    }
    if (RELU) {
#pragma unroll
        for (int i = 0; i < 8; i++) acc[i] = fmaxf(acc[i], 0.f);
    }
    uint4 o;
    o.x = pack2(acc[0], acc[1]);
    o.y = pack2(acc[2], acc[3]);
    o.z = pack2(acc[4], acc[5]);
    o.w = pack2(acc[6], acc[7]);
    ((uint4*)O)[(size_t)node * TPN + part] = o;
}

// ---------------- decode: out[e] = sigmoid(dot(Y[src], Z[dst]) + bb), bf16 in ----------------
__global__ __launch_bounds__(256) void decode_kernel(const u16* __restrict__ Y,
                                                     const u16* __restrict__ Z,
                                                     const int* __restrict__ src,
                                                     const int* __restrict__ dst,
                                                     const float* __restrict__ bb,
                                                     float* __restrict__ out, int E) {
    const uint4* Yv = (const uint4*)Y;
    const uint4* Zv = (const uint4*)Z;
    int tid = blockIdx.x * 256 + threadIdx.x;
    int e = tid / 8;
    int lane = tid % 8;
    if (e >= E) return;
    int s = src[e], d = dst[e];
    uint4 y = Yv[(size_t)s * 8 + lane];
    uint4 z = Zv[(size_t)d * 8 + lane];
    float p = bflo(y.x) * bflo(z.x) + bfhi(y.x) * bfhi(z.x)
            + bflo(y.y) * bflo(z.y) + bfhi(y.y) * bfhi(z.y)
            + bflo(y.z) * bflo(z.z) + bfhi(y.z) * bfhi(z.z)
            + bflo(y.w) * bflo(z.w) + bfhi(y.w) * bfhi(z.w);
    p += __shfl_down(p, 4, 8);
    p += __shfl_down(p, 2, 8);
    p += __shfl_down(p, 1, 8);
    if (lane == 0) out[e] = 1.0f / (1.0f + expf(-(p + bb[0])));
}

extern "C" void kernel_launch(void* const* d_in, const int* in_sizes, int n_in,
                              void* d_out, int out_size, void* d_ws, size_t ws_size,
                              hipStream_t stream) {
    const float* x  = (const float*)d_in[0];
    const int*   ei = (const int*)d_in[1];
    const float* W1 = (const float*)d_in[2];
    const float* b1 = (const float*)d_in[3];
    const float* W2 = (const float*)d_in[4];
    const float* b2 = (const float*)d_in[5];
    const float* Wb = (const float*)d_in[6];
    const float* bb = (const float*)d_in[7];
    float* out = (float*)d_out;

    const int N = N_NODES;
    const int E = in_sizes[1] / 2;
    const int* src = ei;
    const int* dst = ei + E;
    const int NBLK = (N + 1023) / 1024;
    const int GBLK = (N + 127) / 128;

    // workspace layout
    char* w = (char*)d_ws;
    int*   degc    = (int*)w;   w += (size_t)N * 4;
    int*   row_ptr = (int*)w;   w += (size_t)(N + 1) * 4;
    int*   cursor  = (int*)w;   w += (size_t)N * 4;
    int*   blk_sum = (int*)w;   w += (size_t)64 * 4;
    int*   col     = (int*)w;   w += (size_t)E * 4;
    float* dinv    = (float*)w; w += (size_t)N * 4;
    float* inv     = (float*)w; w += (size_t)N * 4;
    w = (char*)(((size_t)w + 15) & ~(size_t)15);
    u16* bufA = (u16*)w;        w += (size_t)N * 128 * 2;  // H1; later H2 / Y
    u16* bufB = (u16*)w;        w += (size_t)N * 128 * 2;  // h1
    u16* bufC = (u16*)w;                                   // Z

    u16* H1 = bufA;
    u16* h1 = bufB;
    u16* H2 = bufA;
    u16* Z  = bufC;
    u16* Y  = bufA + (size_t)N * 64;

    // CSR build + norms
    hipMemsetAsync(degc, 0, (size_t)N * 4, stream);
    deg_count<<<(E + 255) / 256, 256, 0, stream>>>(dst, degc, E);
    deg_fin<<<(N + 255) / 256, 256, 0, stream>>>(degc, dinv, inv, N);
    scan_phase1<<<NBLK, 1024, 0, stream>>>(degc, row_ptr, blk_sum, N);
    scan_phase2<<<1, 64, 0, stream>>>(blk_sum, row_ptr + N, NBLK, E);
    scan_phase3<<<NBLK, 1024, 0, stream>>>(row_ptr, cursor, blk_sum, N);
    csr_fill<<<(E + 255) / 256, 256, 0, stream>>>(src, dst, cursor, col, E);

    // layer 1
    gemm_mfma<128, 128, false><<<GBLK, 256, 0, stream>>>(x, W1, H1, N);
    agg_pull<128, true><<<((size_t)N * 16 + 255) / 256, 256, 0, stream>>>(
        H1, row_ptr, col, dinv, inv, b1, h1, N);

    // layer 2
    gemm_mfma<128, 64, true><<<GBLK, 256, 0, stream>>>(h1, W2, H2, N);
    agg_pull<64, false><<<((size_t)N * 8 + 255) / 256, 256, 0, stream>>>(
        H2, row_ptr, col, dinv, inv, b2, Z, N);

    // decode
    gemm_mfma<64, 64, true><<<GBLK, 256, 0, stream>>>(Z, Wb, Y, N);
    decode_kernel<<<((size_t)E * 8 + 255) / 256, 256, 0, stream>>>(Y, Z, src, dst, bb, out, E);
}

// Round 6
// 297.525 us; speedup vs baseline: 7.7271x; 1.0760x over previous
//
#include <hip/hip_runtime.h>
#include <hip/hip_bf16.h>

// GAE: h1 = relu(gcn(x,W1,b1)); z = gcn(h1,W2,b2); out = sigmoid(dot(Y[src], z[dst]) + bb)
// where Y = z @ Wb[0]  (bilinear refactor).
// PULL aggregation over on-device CSR; gathered node matrices bf16.
// GEMMs: MFMA bf16 with split-bf16 (hi+lo) f32 emulation for f32 operands.
// CSR build: 2-level bucket sort (round-5 csr_fill scattered 4B stores cost
// 64B writebacks each -> 51.7 MB WRITE_SIZE for a 3.2 MB payload).

#define N_NODES 50000
#define BSH 7
#define BSZ 128                       // nodes per bucket
#define NBUCK ((N_NODES + BSZ - 1) / BSZ)   // 391
#define EPB 4096                      // edges per bucket_scatter block

typedef unsigned int u32;
typedef unsigned short u16;

typedef __attribute__((ext_vector_type(8))) short bf16x8;
typedef __attribute__((ext_vector_type(4))) float f32x4;
union frag_u { bf16x8 f; u32 u[4]; uint4 v; };

__device__ __forceinline__ float bflo(u32 u) { return __uint_as_float(u << 16); }
__device__ __forceinline__ float bfhi(u32 u) { return __uint_as_float(u & 0xffff0000u); }
__device__ __forceinline__ u32 f2bf(float f) {  // RNE, returns low 16
    u32 b = __float_as_uint(f);
    return (b + 0x7fffu + ((b >> 16) & 1u)) >> 16;
}
__device__ __forceinline__ u32 pack2(float a, float b) { return f2bf(a) | (f2bf(b) << 16); }

// ---------------- degree histogram (int) ----------------
__global__ __launch_bounds__(256) void deg_count(const int* __restrict__ dst,
                                                 int* __restrict__ degc, int E) {
    int e = blockIdx.x * 256 + threadIdx.x;
    if (e < E) atomicAdd(&degc[dst[e]], 1);
}

__global__ __launch_bounds__(256) void deg_fin(const int* __restrict__ degc,
                                               float* __restrict__ dinv,
                                               float* __restrict__ inv, int n) {
    int i = blockIdx.x * 256 + threadIdx.x;
    if (i < n) {
        float d = (float)degc[i] + 1.0f;
        dinv[i] = rsqrtf(d);
        inv[i] = 1.0f / d;
    }
}

// ---------------- 3-phase exclusive scan: degc -> row_ptr ----------------
__global__ __launch_bounds__(1024) void scan_phase1(const int* __restrict__ degc,
                                                    int* __restrict__ row_ptr,
                                                    int* __restrict__ blk_sum, int n) {
    __shared__ int tmp[1024];
    int i = blockIdx.x * 1024 + threadIdx.x;
    int v = (i < n) ? degc[i] : 0;
    tmp[threadIdx.x] = v;
    __syncthreads();
    for (int off = 1; off < 1024; off <<= 1) {
        int t = (threadIdx.x >= (unsigned)off) ? tmp[threadIdx.x - off] : 0;
        __syncthreads();
        tmp[threadIdx.x] += t;
        __syncthreads();
    }
    if (i < n) row_ptr[i] = tmp[threadIdx.x] - v;
    if (threadIdx.x == 1023) blk_sum[blockIdx.x] = tmp[1023];
}

__global__ __launch_bounds__(64) void scan_phase2(int* __restrict__ blk_sum,
                                                  int* __restrict__ row_ptr_n,
                                                  int nblk, int total) {
    int t = threadIdx.x;
    int v = (t < nblk) ? blk_sum[t] : 0;
    int s = v;
#pragma unroll
    for (int off = 1; off < 64; off <<= 1) {
        int u = __shfl_up(s, off, 64);
        if (t >= off) s += u;
    }
    if (t < nblk) blk_sum[t] = s - v;
    if (t == 0) *row_ptr_n = total;
}

__global__ __launch_bounds__(1024) void scan_phase3(int* __restrict__ row_ptr,
                                                    const int* __restrict__ blk_sum, int n) {
    int i = blockIdx.x * 1024 + threadIdx.x;
    if (i < n) row_ptr[i] += blk_sum[blockIdx.x];
}

// ---------------- bucketed CSR build ----------------
// bucket b covers nodes [b*128,(b+1)*128); its pair region == col region
// [row_ptr[b*128], row_ptr[end]) since buckets partition dst exactly.
__global__ __launch_bounds__(256) void bucket_init(const int* __restrict__ row_ptr,
                                                   int* __restrict__ bcur, int n) {
    int b = blockIdx.x * 256 + threadIdx.x;
    if (b < NBUCK) bcur[b] = row_ptr[b << BSH];
}

// LDS multisplit: per-block histogram -> one global reservation per (block,bucket)
// -> packed 4B records (src | local_dst<<16) written in per-bucket runs.
__global__ __launch_bounds__(256) void bucket_scatter(const int* __restrict__ src,
                                                      const int* __restrict__ dst,
                                                      int* __restrict__ bcur,
                                                      u32* __restrict__ pair, int E) {
    __shared__ int hist[NBUCK];
    for (int i = threadIdx.x; i < NBUCK; i += 256) hist[i] = 0;
    __syncthreads();
    int base = blockIdx.x * EPB;
    int s_[16], d_[16];
#pragma unroll
    for (int it = 0; it < 16; it++) {
        int e = base + it * 256 + threadIdx.x;
        if (e < E) {
            s_[it] = src[e];
            d_[it] = dst[e];
            atomicAdd(&hist[d_[it] >> BSH], 1);
        } else {
            d_[it] = -1;
        }
    }
    __syncthreads();
    for (int b = threadIdx.x; b < NBUCK; b += 256) {
        int c = hist[b];
        hist[b] = c ? atomicAdd(&bcur[b], c) : 0;   // global base for this block's chunk
    }
    __syncthreads();
#pragma unroll
    for (int it = 0; it < 16; it++) {
        if (d_[it] >= 0) {
            int b = d_[it] >> BSH;
            int off = atomicAdd(&hist[b], 1);       // LDS: unique slot in chunk
            pair[off] = (u32)s_[it] | ((u32)(d_[it] & (BSZ - 1)) << 16);
        }
    }
}

// one block per bucket: coalesced read of pair range, col writes confined to
// the bucket's contiguous (L2-resident) window.
__global__ __launch_bounds__(256) void bucket_sort(const u32* __restrict__ pair,
                                                   const int* __restrict__ row_ptr,
                                                   int* __restrict__ col, int n) {
    __shared__ int rp[BSZ + 1];
    __shared__ int cur[BSZ];
    int base = blockIdx.x << BSH;
    int nn = min(BSZ, n - base);
    for (int i = threadIdx.x; i <= nn; i += 256) rp[i] = row_ptr[base + i];
    for (int i = threadIdx.x; i < BSZ; i += 256) cur[i] = 0;
    __syncthreads();
    int j1 = rp[nn];
    for (int j = rp[0] + threadIdx.x; j < j1; j += 256) {
        u32 p = pair[j];
        int ln = (int)(p >> 16);
        int pos = rp[ln] + atomicAdd(&cur[ln], 1);
        col[pos] = (int)(p & 0xffffu);
    }
}

// ---------------- MFMA GEMM: O[n_rows,NOUT](bf16) = X[n_rows,K] @ W[K,NOUT](f32) ----------------
template <int K, int NOUT, bool A_BF16>
__global__ __launch_bounds__(256) void gemm_mfma(const void* __restrict__ Xv,
                                                 const float* __restrict__ W,
                                                 u16* __restrict__ O, int n_rows) {
    constexpr int KP = K + 8;
    constexpr int NT = NOUT / 16;
    constexpr int KS = K / 32;
    __shared__ __align__(16) u16 Wt_hi[NOUT * KP];
    __shared__ __align__(16) u16 Wt_lo[NOUT * KP];
    int t = threadIdx.x;
    for (int i4 = t; i4 < K * NOUT / 4; i4 += 256) {
        int k = (i4 * 4) / NOUT;
        int n0 = (i4 * 4) % NOUT;
        float4 w4 = *(const float4*)&W[(size_t)k * NOUT + n0];
        float wv[4] = {w4.x, w4.y, w4.z, w4.w};
#pragma unroll
        for (int q = 0; q < 4; q++) {
            u32 hi = f2bf(wv[q]);
            u32 lo = f2bf(wv[q] - bflo(hi));
            Wt_hi[(n0 + q) * KP + k] = (u16)hi;
            Wt_lo[(n0 + q) * KP + k] = (u16)lo;
        }
    }
    __syncthreads();

    int wave = t >> 6;
    int lane = t & 63;
    int m16 = lane & 15;
    int quad = lane >> 4;
    int row0 = blockIdx.x * 128 + wave * 32;

    f32x4 acc[2][NT] = {};
    for (int ks = 0; ks < KS; ks++) {
        frag_u a_hi[2], a_lo[2];
#pragma unroll
        for (int mt = 0; mt < 2; mt++) {
            int row = row0 + mt * 16 + m16;
            row = row < n_rows ? row : n_rows - 1;
            if (A_BF16) {
                a_hi[mt].v = *(const uint4*)((const u16*)Xv + (size_t)row * K + ks * 32 + quad * 8);
            } else {
                const float* X = (const float*)Xv + (size_t)row * K + ks * 32 + quad * 8;
                float4 x0 = *(const float4*)X;
                float4 x1 = *(const float4*)(X + 4);
                float xv[8] = {x0.x, x0.y, x0.z, x0.w, x1.x, x1.y, x1.z, x1.w};
#pragma unroll
                for (int p = 0; p < 4; p++) {
                    u32 h0 = f2bf(xv[2 * p]), h1 = f2bf(xv[2 * p + 1]);
                    a_hi[mt].u[p] = h0 | (h1 << 16);
                    a_lo[mt].u[p] = pack2(xv[2 * p] - bflo(h0), xv[2 * p + 1] - bflo(h1));
                }
            }
        }
#pragma unroll
        for (int nt = 0; nt < NT; nt++) {
            int n = nt * 16 + m16;
            frag_u b_hi, b_lo;
            b_hi.v = *(const uint4*)&Wt_hi[n * KP + ks * 32 + quad * 8];
            b_lo.v = *(const uint4*)&Wt_lo[n * KP + ks * 32 + quad * 8];
#pragma unroll
            for (int mt = 0; mt < 2; mt++) {
                acc[mt][nt] = __builtin_amdgcn_mfma_f32_16x16x32_bf16(a_hi[mt].f, b_hi.f, acc[mt][nt], 0, 0, 0);
                acc[mt][nt] = __builtin_amdgcn_mfma_f32_16x16x32_bf16(a_hi[mt].f, b_lo.f, acc[mt][nt], 0, 0, 0);
                if (!A_BF16)
                    acc[mt][nt] = __builtin_amdgcn_mfma_f32_16x16x32_bf16(a_lo[mt].f, b_hi.f, acc[mt][nt], 0, 0, 0);
            }
        }
    }
#pragma unroll
    for (int mt = 0; mt < 2; mt++)
#pragma unroll
        for (int nt = 0; nt < NT; nt++)
#pragma unroll
            for (int r = 0; r < 4; r++) {
                int row = row0 + mt * 16 + quad * 4 + r;
                if (row < n_rows)
                    O[(size_t)row * NOUT + nt * 16 + m16] = (u16)f2bf(acc[mt][nt][r]);
            }
}

// ---------------- pull aggregation + self-loop + bias (+relu), bf16 in/out ----------------
template <int C, bool RELU>
__global__ __launch_bounds__(256) void agg_pull(const u16* __restrict__ H,
                                                const int* __restrict__ row_ptr,
                                                const int* __restrict__ col,
                                                const float* __restrict__ dinv,
                                                const float* __restrict__ inv,
                                                const float* __restrict__ b,
                                                u16* __restrict__ O, int n) {
    constexpr int TPN = C / 8;
    const uint4* Hv = (const uint4*)H;
    int tid = blockIdx.x * 256 + threadIdx.x;
    int node = tid / TPN;
    if (node >= n) return;
    int part = tid % TPN;
    int c8 = part * 8;
    float dn = dinv[node];
    float iv = inv[node];
    float acc[8];
    {
        uint4 h = Hv[(size_t)node * TPN + part];
        acc[0] = bflo(h.x) * iv + b[c8 + 0];
        acc[1] = bfhi(h.x) * iv + b[c8 + 1];
        acc[2] = bflo(h.y) * iv + b[c8 + 2];
        acc[3] = bfhi(h.y) * iv + b[c8 + 3];
        acc[4] = bflo(h.z) * iv + b[c8 + 4];
        acc[5] = bfhi(h.z) * iv + b[c8 + 5];
        acc[6] = bflo(h.w) * iv + b[c8 + 6];
        acc[7] = bfhi(h.w) * iv + b[c8 + 7];
    }
    int j = row_ptr[node];
    int end = row_ptr[node + 1];
    for (; j + 3 < end; j += 4) {
        int s0 = col[j], s1 = col[j + 1], s2 = col[j + 2], s3 = col[j + 3];
        float n0 = dn * dinv[s0], n1 = dn * dinv[s1];
        float n2 = dn * dinv[s2], n3 = dn * dinv[s3];
        uint4 v0 = Hv[(size_t)s0 * TPN + part];
        uint4 v1 = Hv[(size_t)s1 * TPN + part];
        uint4 v2 = Hv[(size_t)s2 * TPN + part];
        uint4 v3 = Hv[(size_t)s3 * TPN + part];
        acc[0] += bflo(v0.x) * n0 + bflo(v1.x) * n1 + bflo(v2.x) * n2 + bflo(v3.x) * n3;
        acc[1] += bfhi(v0.x) * n0 + bfhi(v1.x) * n1 + bfhi(v2.x) * n2 + bfhi(v3.x) * n3;
        acc[2] += bflo(v0.y) * n0 + bflo(v1.y) * n1 + bflo(v2.y) * n2 + bflo(v3.y) * n3;
        acc[3] += bfhi(v0.y) * n0 + bfhi(v1.y) * n1 + bfhi(v2.y) * n2 + bfhi(v3.y) * n3;
        acc[4] += bflo(v0.z) * n0 + bflo(v1.z) * n1 + bflo(v2.z) * n2 + bflo(v3.z) * n3;
        acc[5] += bfhi(v0.z) * n0 + bfhi(v1.z) * n1 + bfhi(v2.z) * n2 + bfhi(v3.z) * n3;
        acc[6] += bflo(v0.w) * n0 + bflo(v1.w) * n1 + bflo(v2.w) * n2 + bflo(v3.w) * n3;
        acc[7] += bfhi(v0.w) * n0 + bfhi(v1.w) * n1 + bfhi(v2.w) * n2 + bfhi(v3.w) * n3;
    }
    for (; j < end; j++) {
        int s = col[j];
        float nm = dn * dinv[s];
        uint4 v = Hv[(size_t)s * TPN + part];
        acc[0] += bflo(v.x) * nm; acc[1] += bfhi(v.x) * nm;
        acc[2] += bflo(v.y) * nm; acc[3] += bfhi(v.y) * nm;
        acc[4] += bflo(v.z) * nm; acc[5] += bfhi(v.z) * nm;
        acc[6] += bflo(v.w) * nm; acc[7] += bfhi(v.w) * nm;
    }
    if (RELU) {
#pragma unroll
        for (int i = 0; i < 8; i++) acc[i] = fmaxf(acc[i], 0.f);
    }
    uint4 o;
    o.x = pack2(acc[0], acc[1]);
    o.y = pack2(acc[2], acc[3]);
    o.z = pack2(acc[4], acc[5]);
    o.w = pack2(acc[6], acc[7]);
    ((uint4*)O)[(size_t)node * TPN + part] = o;
}

// ---------------- decode: out[e] = sigmoid(dot(Y[src], Z[dst]) + bb), bf16 in ----------------
__global__ __launch_bounds__(256) void decode_kernel(const u16* __restrict__ Y,
                                                     const u16* __restrict__ Z,
                                                     const int* __restrict__ src,
                                                     const int* __restrict__ dst,
                                                     const float* __restrict__ bb,
                                                     float* __restrict__ out, int E) {
    const uint4* Yv = (const uint4*)Y;
    const uint4* Zv = (const uint4*)Z;
    int tid = blockIdx.x * 256 + threadIdx.x;
    int e = tid / 8;
    int lane = tid % 8;
    if (e >= E) return;
    int s = src[e], d = dst[e];
    uint4 y = Yv[(size_t)s * 8 + lane];
    uint4 z = Zv[(size_t)d * 8 + lane];
    float p = bflo(y.x) * bflo(z.x) + bfhi(y.x) * bfhi(z.x)
            + bflo(y.y) * bflo(z.y) + bfhi(y.y) * bfhi(z.y)
            + bflo(y.z) * bflo(z.z) + bfhi(y.z) * bfhi(z.z)
            + bflo(y.w) * bflo(z.w) + bfhi(y.w) * bfhi(z.w);
    p += __shfl_down(p, 4, 8);
    p += __shfl_down(p, 2, 8);
    p += __shfl_down(p, 1, 8);
    if (lane == 0) out[e] = 1.0f / (1.0f + expf(-(p + bb[0])));
}

extern "C" void kernel_launch(void* const* d_in, const int* in_sizes, int n_in,
                              void* d_out, int out_size, void* d_ws, size_t ws_size,
                              hipStream_t stream) {
    const float* x  = (const float*)d_in[0];
    const int*   ei = (const int*)d_in[1];
    const float* W1 = (const float*)d_in[2];
    const float* b1 = (const float*)d_in[3];
    const float* W2 = (const float*)d_in[4];
    const float* b2 = (const float*)d_in[5];
    const float* Wb = (const float*)d_in[6];
    const float* bb = (const float*)d_in[7];
    float* out = (float*)d_out;

    const int N = N_NODES;
    const int E = in_sizes[1] / 2;
    const int* src = ei;
    const int* dst = ei + E;
    const int NBLK = (N + 1023) / 1024;
    const int GBLK = (N + 127) / 128;

    // workspace layout
    char* w = (char*)d_ws;
    int*   degc    = (int*)w;   w += (size_t)N * 4;
    int*   row_ptr = (int*)w;   w += (size_t)(N + 1) * 4;
    int*   bcur    = (int*)w;   w += (size_t)512 * 4;
    int*   blk_sum = (int*)w;   w += (size_t)64 * 4;
    int*   col     = (int*)w;   w += (size_t)E * 4;
    u32*   pair    = (u32*)w;   w += (size_t)E * 4;
    float* dinv    = (float*)w; w += (size_t)N * 4;
    float* inv     = (float*)w; w += (size_t)N * 4;
    w = (char*)(((size_t)w + 15) & ~(size_t)15);
    u16* bufA = (u16*)w;        w += (size_t)N * 128 * 2;  // H1; later H2 / Y
    u16* bufB = (u16*)w;        w += (size_t)N * 128 * 2;  // h1
    u16* bufC = (u16*)w;                                   // Z

    u16* H1 = bufA;
    u16* h1 = bufB;
    u16* H2 = bufA;
    u16* Z  = bufC;
    u16* Y  = bufA + (size_t)N * 64;

    // CSR build + norms
    hipMemsetAsync(degc, 0, (size_t)N * 4, stream);
    deg_count<<<(E + 255) / 256, 256, 0, stream>>>(dst, degc, E);
    deg_fin<<<(N + 255) / 256, 256, 0, stream>>>(degc, dinv, inv, N);
    scan_phase1<<<NBLK, 1024, 0, stream>>>(degc, row_ptr, blk_sum, N);
    scan_phase2<<<1, 64, 0, stream>>>(blk_sum, row_ptr + N, NBLK, E);
    scan_phase3<<<NBLK, 1024, 0, stream>>>(row_ptr, blk_sum, N);
    bucket_init<<<(NBUCK + 255) / 256, 256, 0, stream>>>(row_ptr, bcur, N);
    bucket_scatter<<<(E + EPB - 1) / EPB, 256, 0, stream>>>(src, dst, bcur, pair, E);
    bucket_sort<<<NBUCK, 256, 0, stream>>>(pair, row_ptr, col, N);

    // layer 1
    gemm_mfma<128, 128, false><<<GBLK, 256, 0, stream>>>(x, W1, H1, N);
    agg_pull<128, true><<<((size_t)N * 16 + 255) / 256, 256, 0, stream>>>(
        H1, row_ptr, col, dinv, inv, b1, h1, N);

    // layer 2
    gemm_mfma<128, 64, true><<<GBLK, 256, 0, stream>>>(h1, W2, H2, N);
    agg_pull<64, false><<<((size_t)N * 8 + 255) / 256, 256, 0, stream>>>(
        H2, row_ptr, col, dinv, inv, b2, Z, N);

    // decode
    gemm_mfma<64, 64, true><<<GBLK, 256, 0, stream>>>(Z, Wb, Y, N);
    decode_kernel<<<((size_t)E * 8 + 255) / 256, 256, 0, stream>>>(Y, Z, src, dst, bb, out, E);
}

// Round 7
// 259.845 us; speedup vs baseline: 8.8476x; 1.1450x over previous
//
#include <hip/hip_runtime.h>
#include <hip/hip_bf16.h>

// GAE: h1 = relu(gcn(x,W1,b1)); z = gcn(h1,W2,b2); out = sigmoid(dot(Y[src], z[dst]) + bb)
// where Y = z @ Wb[0]  (bilinear refactor).
// PULL aggregation over on-device CSR; gathered node matrices bf16.
// GEMMs: MFMA bf16 with split-bf16 (hi+lo) f32 emulation for f32 operands.
// CSR build: fully bucketed — per-bucket histogram -> 391-wide scan ->
// multisplit scatter -> per-bucket sort that ALSO computes row_ptr/deg/dinv/inv
// (round-6 front-end spent ~6 dispatches + 800k global atomics on degrees/scan).

#define N_NODES 50000
#define BSH 7
#define BSZ 128                             // nodes per bucket
#define NBUCK ((N_NODES + BSZ - 1) / BSZ)   // 391
#define EPB 4096                            // edges per bucket_scatter block

typedef unsigned int u32;
typedef unsigned short u16;

typedef __attribute__((ext_vector_type(8))) short bf16x8;
typedef __attribute__((ext_vector_type(4))) float f32x4;
union frag_u { bf16x8 f; u32 u[4]; uint4 v; };

__device__ __forceinline__ float bflo(u32 u) { return __uint_as_float(u << 16); }
__device__ __forceinline__ float bfhi(u32 u) { return __uint_as_float(u & 0xffff0000u); }
__device__ __forceinline__ u32 f2bf(float f) {  // RNE, returns low 16
    u32 b = __float_as_uint(f);
    return (b + 0x7fffu + ((b >> 16) & 1u)) >> 16;
}
__device__ __forceinline__ u32 pack2(float a, float b) { return f2bf(a) | (f2bf(b) << 16); }

// ---------------- bucket histogram: bhist[b] = #edges with dst in bucket b ----------------
__global__ __launch_bounds__(256) void bucket_hist(const int* __restrict__ dst,
                                                   int* __restrict__ bhist, int E) {
    __shared__ int hist[NBUCK];
    for (int i = threadIdx.x; i < NBUCK; i += 256) hist[i] = 0;
    __syncthreads();
    int base = blockIdx.x * EPB;
    int e1 = min(base + EPB, E);
    for (int e = base + threadIdx.x; e < e1; e += 256)
        atomicAdd(&hist[dst[e] >> BSH], 1);
    __syncthreads();
    for (int b = threadIdx.x; b < NBUCK; b += 256) {
        int c = hist[b];
        if (c) atomicAdd(&bhist[b], c);
    }
}

// ---------------- scan 391 bucket counts -> bbase (excl), bcur ----------------
__global__ __launch_bounds__(512) void bucket_scan(const int* __restrict__ bhist,
                                                   int* __restrict__ bbase,
                                                   int* __restrict__ bcur, int E) {
    __shared__ int tmp[512];
    int t = threadIdx.x;
    int v = (t < NBUCK) ? bhist[t] : 0;
    tmp[t] = v;
    __syncthreads();
    for (int off = 1; off < 512; off <<= 1) {
        int a = (t >= off) ? tmp[t - off] : 0;
        __syncthreads();
        tmp[t] += a;
        __syncthreads();
    }
    int excl = tmp[t] - v;
    if (t < NBUCK) { bbase[t] = excl; bcur[t] = excl; }
    if (t == 0) bbase[NBUCK] = E;
}

// ---------------- multisplit scatter: packed records into bucket regions ----------------
__global__ __launch_bounds__(256) void bucket_scatter(const int* __restrict__ src,
                                                      const int* __restrict__ dst,
                                                      int* __restrict__ bcur,
                                                      u32* __restrict__ pair, int E) {
    __shared__ int hist[NBUCK];
    for (int i = threadIdx.x; i < NBUCK; i += 256) hist[i] = 0;
    __syncthreads();
    int base = blockIdx.x * EPB;
    int s_[16], d_[16];
#pragma unroll
    for (int it = 0; it < 16; it++) {
        int e = base + it * 256 + threadIdx.x;
        if (e < E) {
            s_[it] = src[e];
            d_[it] = dst[e];
            atomicAdd(&hist[d_[it] >> BSH], 1);
        } else {
            d_[it] = -1;
        }
    }
    __syncthreads();
    for (int b = threadIdx.x; b < NBUCK; b += 256) {
        int c = hist[b];
        hist[b] = c ? atomicAdd(&bcur[b], c) : 0;   // global base for this block's chunk
    }
    __syncthreads();
#pragma unroll
    for (int it = 0; it < 16; it++) {
        if (d_[it] >= 0) {
            int b = d_[it] >> BSH;
            int off = atomicAdd(&hist[b], 1);       // LDS: unique slot in chunk
            pair[off] = (u32)s_[it] | ((u32)(d_[it] & (BSZ - 1)) << 16);
        }
    }
}

// ---------------- per-bucket: degrees -> row_ptr/dinv/inv, then place col ----------------
__global__ __launch_bounds__(256) void bucket_sort(const u32* __restrict__ pair,
                                                   const int* __restrict__ bbase,
                                                   int* __restrict__ row_ptr,
                                                   int* __restrict__ col,
                                                   float* __restrict__ dinv,
                                                   float* __restrict__ inv, int n, int E) {
    __shared__ int cnt[BSZ];
    __shared__ int scn[BSZ];
    __shared__ int cur[BSZ];
    int t = threadIdx.x;
    int base = blockIdx.x << BSH;
    int nn = min(BSZ, n - base);
    int b0 = bbase[blockIdx.x];
    int b1 = bbase[blockIdx.x + 1];
    if (t < BSZ) cnt[t] = 0;
    __syncthreads();
    // pass 1: local degree count
    for (int j = b0 + t; j < b1; j += 256)
        atomicAdd(&cnt[pair[j] >> 16], 1);
    __syncthreads();
    // scan 128 counts (Hillis-Steele in LDS)
    if (t < BSZ) scn[t] = cnt[t];
    __syncthreads();
    for (int off = 1; off < BSZ; off <<= 1) {
        int a = (t < BSZ && t >= off) ? scn[t - off] : 0;
        __syncthreads();
        if (t < BSZ) scn[t] += a;
        __syncthreads();
    }
    if (t < nn) {
        int excl = b0 + scn[t] - cnt[t];
        row_ptr[base + t] = excl;
        cur[t] = excl;
        float d = (float)cnt[t] + 1.0f;
        dinv[base + t] = rsqrtf(d);
        inv[base + t] = 1.0f / d;
    }
    if (t == 0 && blockIdx.x == NBUCK - 1) row_ptr[n] = E;
    __syncthreads();
    // pass 2: place
    for (int j = b0 + t; j < b1; j += 256) {
        u32 p = pair[j];
        int ln = (int)(p >> 16);
        int pos = atomicAdd(&cur[ln], 1);
        col[pos] = (int)(p & 0xffffu);
    }
}

// ---------------- MFMA GEMM: O[n_rows,NOUT](bf16) = X[n_rows,K] @ W[K,NOUT](f32) ----------------
template <int K, int NOUT, bool A_BF16>
__global__ __launch_bounds__(256) void gemm_mfma(const void* __restrict__ Xv,
                                                 const float* __restrict__ W,
                                                 u16* __restrict__ O, int n_rows) {
    constexpr int KP = K + 8;
    constexpr int NT = NOUT / 16;
    constexpr int KS = K / 32;
    __shared__ __align__(16) u16 Wt_hi[NOUT * KP];
    __shared__ __align__(16) u16 Wt_lo[NOUT * KP];
    int t = threadIdx.x;
    for (int i4 = t; i4 < K * NOUT / 4; i4 += 256) {
        int k = (i4 * 4) / NOUT;
        int n0 = (i4 * 4) % NOUT;
        float4 w4 = *(const float4*)&W[(size_t)k * NOUT + n0];
        float wv[4] = {w4.x, w4.y, w4.z, w4.w};
#pragma unroll
        for (int q = 0; q < 4; q++) {
            u32 hi = f2bf(wv[q]);
            u32 lo = f2bf(wv[q] - bflo(hi));
            Wt_hi[(n0 + q) * KP + k] = (u16)hi;
            Wt_lo[(n0 + q) * KP + k] = (u16)lo;
        }
    }
    __syncthreads();

    int wave = t >> 6;
    int lane = t & 63;
    int m16 = lane & 15;
    int quad = lane >> 4;
    int row0 = blockIdx.x * 128 + wave * 32;

    f32x4 acc[2][NT] = {};
    for (int ks = 0; ks < KS; ks++) {
        frag_u a_hi[2], a_lo[2];
#pragma unroll
        for (int mt = 0; mt < 2; mt++) {
            int row = row0 + mt * 16 + m16;
            row = row < n_rows ? row : n_rows - 1;
            if (A_BF16) {
                a_hi[mt].v = *(const uint4*)((const u16*)Xv + (size_t)row * K + ks * 32 + quad * 8);
            } else {
                const float* X = (const float*)Xv + (size_t)row * K + ks * 32 + quad * 8;
                float4 x0 = *(const float4*)X;
                float4 x1 = *(const float4*)(X + 4);
                float xv[8] = {x0.x, x0.y, x0.z, x0.w, x1.x, x1.y, x1.z, x1.w};
#pragma unroll
                for (int p = 0; p < 4; p++) {
                    u32 h0 = f2bf(xv[2 * p]), h1 = f2bf(xv[2 * p + 1]);
                    a_hi[mt].u[p] = h0 | (h1 << 16);
                    a_lo[mt].u[p] = pack2(xv[2 * p] - bflo(h0), xv[2 * p + 1] - bflo(h1));
                }
            }
        }
#pragma unroll
        for (int nt = 0; nt < NT; nt++) {
            int n = nt * 16 + m16;
            frag_u b_hi, b_lo;
            b_hi.v = *(const uint4*)&Wt_hi[n * KP + ks * 32 + quad * 8];
            b_lo.v = *(const uint4*)&Wt_lo[n * KP + ks * 32 + quad * 8];
#pragma unroll
            for (int mt = 0; mt < 2; mt++) {
                acc[mt][nt] = __builtin_amdgcn_mfma_f32_16x16x32_bf16(a_hi[mt].f, b_hi.f, acc[mt][nt], 0, 0, 0);
                acc[mt][nt] = __builtin_amdgcn_mfma_f32_16x16x32_bf16(a_hi[mt].f, b_lo.f, acc[mt][nt], 0, 0, 0);
                if (!A_BF16)
                    acc[mt][nt] = __builtin_amdgcn_mfma_f32_16x16x32_bf16(a_lo[mt].f, b_hi.f, acc[mt][nt], 0, 0, 0);
            }
        }
    }
#pragma unroll
    for (int mt = 0; mt < 2; mt++)
#pragma unroll
        for (int nt = 0; nt < NT; nt++)
#pragma unroll
            for (int r = 0; r < 4; r++) {
                int row = row0 + mt * 16 + quad * 4 + r;
                if (row < n_rows)
                    O[(size_t)row * NOUT + nt * 16 + m16] = (u16)f2bf(acc[mt][nt][r]);
            }
}

// ---------------- pull aggregation + self-loop + bias (+relu), bf16 in/out ----------------
template <int C, bool RELU>
__global__ __launch_bounds__(256) void agg_pull(const u16* __restrict__ H,
                                                const int* __restrict__ row_ptr,
                                                const int* __restrict__ col,
                                                const float* __restrict__ dinv,
                                                const float* __restrict__ inv,
                                                const float* __restrict__ b,
                                                u16* __restrict__ O, int n) {
    constexpr int TPN = C / 8;
    const uint4* Hv = (const uint4*)H;
    int tid = blockIdx.x * 256 + threadIdx.x;
    int node = tid / TPN;
    if (node >= n) return;
    int part = tid % TPN;
    int c8 = part * 8;
    float dn = dinv[node];
    float iv = inv[node];
    float acc[8];
    {
        uint4 h = Hv[(size_t)node * TPN + part];
        acc[0] = bflo(h.x) * iv + b[c8 + 0];
        acc[1] = bfhi(h.x) * iv + b[c8 + 1];
        acc[2] = bflo(h.y) * iv + b[c8 + 2];
        acc[3] = bfhi(h.y) * iv + b[c8 + 3];
        acc[4] = bflo(h.z) * iv + b[c8 + 4];
        acc[5] = bfhi(h.z) * iv + b[c8 + 5];
        acc[6] = bflo(h.w) * iv + b[c8 + 6];
        acc[7] = bfhi(h.w) * iv + b[c8 + 7];
    }
    int j = row_ptr[node];
    int end = row_ptr[node + 1];
    for (; j + 3 < end; j += 4) {
        int s0 = col[j], s1 = col[j + 1], s2 = col[j + 2], s3 = col[j + 3];
        float n0 = dn * dinv[s0], n1 = dn * dinv[s1];
        float n2 = dn * dinv[s2], n3 = dn * dinv[s3];
        uint4 v0 = Hv[(size_t)s0 * TPN + part];
        uint4 v1 = Hv[(size_t)s1 * TPN + part];
        uint4 v2 = Hv[(size_t)s2 * TPN + part];
        uint4 v3 = Hv[(size_t)s3 * TPN + part];
        acc[0] += bflo(v0.x) * n0 + bflo(v1.x) * n1 + bflo(v2.x) * n2 + bflo(v3.x) * n3;
        acc[1] += bfhi(v0.x) * n0 + bfhi(v1.x) * n1 + bfhi(v2.x) * n2 + bfhi(v3.x) * n3;
        acc[2] += bflo(v0.y) * n0 + bflo(v1.y) * n1 + bflo(v2.y) * n2 + bflo(v3.y) * n3;
        acc[3] += bfhi(v0.y) * n0 + bfhi(v1.y) * n1 + bfhi(v2.y) * n2 + bfhi(v3.y) * n3;
        acc[4] += bflo(v0.z) * n0 + bflo(v1.z) * n1 + bflo(v2.z) * n2 + bflo(v3.z) * n3;
        acc[5] += bfhi(v0.z) * n0 + bfhi(v1.z) * n1 + bfhi(v2.z) * n2 + bfhi(v3.z) * n3;
        acc[6] += bflo(v0.w) * n0 + bflo(v1.w) * n1 + bflo(v2.w) * n2 + bflo(v3.w) * n3;
        acc[7] += bfhi(v0.w) * n0 + bfhi(v1.w) * n1 + bfhi(v2.w) * n2 + bfhi(v3.w) * n3;
    }
    for (; j < end; j++) {
        int s = col[j];
        float nm = dn * dinv[s];
        uint4 v = Hv[(size_t)s * TPN + part];
        acc[0] += bflo(v.x) * nm; acc[1] += bfhi(v.x) * nm;
        acc[2] += bflo(v.y) * nm; acc[3] += bfhi(v.y) * nm;
        acc[4] += bflo(v.z) * nm; acc[5] += bfhi(v.z) * nm;
        acc[6] += bflo(v.w) * nm; acc[7] += bfhi(v.w) * nm;
    }
    if (RELU) {
#pragma unroll
        for (int i = 0; i < 8; i++) acc[i] = fmaxf(acc[i], 0.f);
    }
    uint4 o;
    o.x = pack2(acc[0], acc[1]);
    o.y = pack2(acc[2], acc[3]);
    o.z = pack2(acc[4], acc[5]);
    o.w = pack2(acc[6], acc[7]);
    ((uint4*)O)[(size_t)node * TPN + part] = o;
}

// ---------------- decode: out[e] = sigmoid(dot(Y[src], Z[dst]) + bb), bf16 in ----------------
__global__ __launch_bounds__(256) void decode_kernel(const u16* __restrict__ Y,
                                                     const u16* __restrict__ Z,
                                                     const int* __restrict__ src,
                                                     const int* __restrict__ dst,
                                                     const float* __restrict__ bb,
                                                     float* __restrict__ out, int E) {
    const uint4* Yv = (const uint4*)Y;
    const uint4* Zv = (const uint4*)Z;
    int tid = blockIdx.x * 256 + threadIdx.x;
    int e = tid / 8;
    int lane = tid % 8;
    if (e >= E) return;
    int s = src[e], d = dst[e];
    uint4 y = Yv[(size_t)s * 8 + lane];
    uint4 z = Zv[(size_t)d * 8 + lane];
    float p = bflo(y.x) * bflo(z.x) + bfhi(y.x) * bfhi(z.x)
            + bflo(y.y) * bflo(z.y) + bfhi(y.y) * bfhi(z.y)
            + bflo(y.z) * bflo(z.z) + bfhi(y.z) * bfhi(z.z)
            + bflo(y.w) * bflo(z.w) + bfhi(y.w) * bfhi(z.w);
    p += __shfl_down(p, 4, 8);
    p += __shfl_down(p, 2, 8);
    p += __shfl_down(p, 1, 8);
    if (lane == 0) out[e] = 1.0f / (1.0f + expf(-(p + bb[0])));
}

extern "C" void kernel_launch(void* const* d_in, const int* in_sizes, int n_in,
                              void* d_out, int out_size, void* d_ws, size_t ws_size,
                              hipStream_t stream) {
    const float* x  = (const float*)d_in[0];
    const int*   ei = (const int*)d_in[1];
    const float* W1 = (const float*)d_in[2];
    const float* b1 = (const float*)d_in[3];
    const float* W2 = (const float*)d_in[4];
    const float* b2 = (const float*)d_in[5];
    const float* Wb = (const float*)d_in[6];
    const float* bb = (const float*)d_in[7];
    float* out = (float*)d_out;

    const int N = N_NODES;
    const int E = in_sizes[1] / 2;
    const int* src = ei;
    const int* dst = ei + E;
    const int GBLK = (N + 127) / 128;
    const int SBLK = (E + EPB - 1) / EPB;

    // workspace layout
    char* w = (char*)d_ws;
    int*   bhist   = (int*)w;   w += (size_t)512 * 4;
    int*   bbase   = (int*)w;   w += (size_t)512 * 4;
    int*   bcur    = (int*)w;   w += (size_t)512 * 4;
    int*   row_ptr = (int*)w;   w += (size_t)(N + 1) * 4;
    int*   col     = (int*)w;   w += (size_t)E * 4;
    u32*   pair    = (u32*)w;   w += (size_t)E * 4;
    float* dinv    = (float*)w; w += (size_t)N * 4;
    float* inv     = (float*)w; w += (size_t)N * 4;
    w = (char*)(((size_t)w + 15) & ~(size_t)15);
    u16* bufA = (u16*)w;        w += (size_t)N * 128 * 2;  // H1; later H2 / Y
    u16* bufB = (u16*)w;        w += (size_t)N * 128 * 2;  // h1
    u16* bufC = (u16*)w;                                   // Z

    u16* H1 = bufA;
    u16* h1 = bufB;
    u16* H2 = bufA;
    u16* Z  = bufC;
    u16* Y  = bufA + (size_t)N * 64;

    // CSR build (degrees, row_ptr, dinv, inv all from bucket machinery)
    hipMemsetAsync(bhist, 0, 512 * 4, stream);
    bucket_hist<<<SBLK, 256, 0, stream>>>(dst, bhist, E);
    bucket_scan<<<1, 512, 0, stream>>>(bhist, bbase, bcur, E);
    bucket_scatter<<<SBLK, 256, 0, stream>>>(src, dst, bcur, pair, E);
    bucket_sort<<<NBUCK, 256, 0, stream>>>(pair, bbase, row_ptr, col, dinv, inv, N, E);

    // layer 1
    gemm_mfma<128, 128, false><<<GBLK, 256, 0, stream>>>(x, W1, H1, N);
    agg_pull<128, true><<<((size_t)N * 16 + 255) / 256, 256, 0, stream>>>(
        H1, row_ptr, col, dinv, inv, b1, h1, N);

    // layer 2
    gemm_mfma<128, 64, true><<<GBLK, 256, 0, stream>>>(h1, W2, H2, N);
    agg_pull<64, false><<<((size_t)N * 8 + 255) / 256, 256, 0, stream>>>(
        H2, row_ptr, col, dinv, inv, b2, Z, N);

    // decode
    gemm_mfma<64, 64, true><<<GBLK, 256, 0, stream>>>(Z, Wb, Y, N);
    decode_kernel<<<((size_t)E * 8 + 255) / 256, 256, 0, stream>>>(Y, Z, src, dst, bb, out, E);
}